// Round 7
// baseline (371.214 us; speedup 1.0000x reference)
//
#include <hip/hip_runtime.h>
#include <hip/hip_bf16.h>
#include <cstdint>

#define H1 8
#define C1 64      // H1*D1
#define D2 128
#define FIN 256
#define NEG 0.2f
#define EPSS 1e-16f
#define CH 1024    // nodes per scan chunk
#define NPW2 8     // gemm2: nodes per wave
#define NPB2 32    // gemm2: nodes per block
#define XPAD 264   // gemm1 LDS row stride in bf16
#define HP 68      // gemm1 epilogue f32 row stride
#define NPBIN 128  // nodes per bin (CSR binning)
#define TILEB 4096 // edges per k_bin block
#define MAXD1 128  // agg1 fast-path degree cap
#define MAXD2 256  // agg2 fast-path degree cap

template<typename T> __device__ __forceinline__ float toF(T v);
template<> __device__ __forceinline__ float toF<float>(float v) { return v; }
template<> __device__ __forceinline__ float toF<__hip_bfloat16>(__hip_bfloat16 v) { return __bfloat162float(v); }
template<typename T> __device__ __forceinline__ T fromF(float v);
template<> __device__ __forceinline__ float fromF<float>(float v) { return v; }
template<> __device__ __forceinline__ __hip_bfloat16 fromF<__hip_bfloat16>(float v) { return __float2bfloat16(v); }

__device__ __forceinline__ float bcast_lane(float v, int lane) {
    return __int_as_float(__builtin_amdgcn_readlane(__float_as_int(v), lane));
}

__device__ __forceinline__ unsigned pk_bf16(float lo, float hi) {
    unsigned a = (unsigned)__bfloat16_as_ushort(__float2bfloat16(lo));
    unsigned b = (unsigned)__bfloat16_as_ushort(__float2bfloat16(hi));
    return a | (b << 16);
}

typedef __attribute__((ext_vector_type(8))) short bf16x8;
typedef __attribute__((ext_vector_type(4))) float f32x4;

// online-softmax chain update (fallback path)
__device__ __forceinline__ void chain_upd(float ev, float hv,
                                          float& m, float& s, float& a)
{
    float mn = fmaxf(m, ev);
    float sc = __expf(m - mn);
    float p  = __expf(ev - mn);
    s = fmaf(s, sc, p);
    a = fmaf(a, sc, p * hv);
    m = mn;
}

// ---------------- GEMM1 (MFMA): h1 = x @ W1, fused alpha_src1/alpha_dst1 ----------------
template<typename T>
__global__ __launch_bounds__(256) void k_gemm1(const float* __restrict__ x,
    const float* __restrict__ W1, const float* __restrict__ a_src1,
    const float* __restrict__ a_dst1, T* __restrict__ h1,
    float* __restrict__ asrc1, float* __restrict__ adst1, int N)
{
    __shared__ alignas(16) unsigned short Xs[64 * XPAD];   // 33.8 KB (reused as f32 Hs)
    __shared__ alignas(16) unsigned short Wt[64 * XPAD];   // 33.8 KB: Wt[col][k]
    int tid = threadIdx.x;
    int wave = tid >> 6, lane = tid & 63;
    int nodeBase = blockIdx.x * 64;

    // stage W1^T bf16
    {
        int c = tid & 63;
        int kb = (tid >> 6) * 4;
        #pragma unroll
        for (int s = 0; s < 16; ++s) {
            int k0 = s * 16 + kb;
            float f0 = W1[(k0 + 0) * C1 + c];
            float f1 = W1[(k0 + 1) * C1 + c];
            float f2 = W1[(k0 + 2) * C1 + c];
            float f3 = W1[(k0 + 3) * C1 + c];
            *reinterpret_cast<uint2*>(&Wt[c * XPAD + k0]) =
                make_uint2(pk_bf16(f0, f1), pk_bf16(f2, f3));
        }
    }
    // stage x tile bf16
    for (int i = tid; i < 64 * 64; i += 256) {
        int r = i >> 6, kq = i & 63;
        int n = nodeBase + r;
        float4 v = (n < N) ? reinterpret_cast<const float4*>(x)[(size_t)n * 64 + kq]
                           : make_float4(0.f, 0.f, 0.f, 0.f);
        *reinterpret_cast<uint2*>(&Xs[r * XPAD + kq * 4]) =
            make_uint2(pk_bf16(v.x, v.y), pk_bf16(v.z, v.w));
    }
    __syncthreads();

    int m = lane & 15;
    int kg = lane >> 4;
    int arow = wave * 16 + m;
    f32x4 acc[4];
    #pragma unroll
    for (int t = 0; t < 4; ++t) acc[t] = (f32x4){0.f, 0.f, 0.f, 0.f};
    #pragma unroll
    for (int ks = 0; ks < 8; ++ks) {
        int k0 = ks * 32 + kg * 8;
        bf16x8 a = *reinterpret_cast<const bf16x8*>(&Xs[arow * XPAD + k0]);
        #pragma unroll
        for (int t = 0; t < 4; ++t) {
            bf16x8 b = *reinterpret_cast<const bf16x8*>(&Wt[(t * 16 + m) * XPAD + k0]);
            acc[t] = __builtin_amdgcn_mfma_f32_16x16x32_bf16(a, b, acc[t], 0, 0, 0);
        }
    }
    __syncthreads();

    float* Hs = reinterpret_cast<float*>(Xs);
    int crow = (lane >> 4) * 4;
    #pragma unroll
    for (int t = 0; t < 4; ++t)
        #pragma unroll
        for (int r = 0; r < 4; ++r)
            Hs[(wave * 16 + crow + r) * HP + t * 16 + m] = acc[t][r];
    __syncthreads();

    float as_l = a_src1[lane], ad_l = a_dst1[lane];
    int n0 = nodeBase + wave * 16;
    #pragma unroll
    for (int i = 0; i < 16; ++i) {
        int n = n0 + i;
        if (n >= N) break;
        float hv = Hs[(wave * 16 + i) * HP + lane];
        h1[(size_t)n * C1 + lane] = fromF<T>(hv);
        float vs = hv * as_l, vd = hv * ad_l;
        #pragma unroll
        for (int off = 1; off < 8; off <<= 1) {
            vs += __shfl_xor(vs, off);
            vd += __shfl_xor(vd, off);
        }
        if ((lane & 7) == 0) {
            asrc1[n * H1 + (lane >> 3)] = vs;
            adst1[n * H1 + (lane >> 3)] = vd;
        }
    }
}

// ---------------- wsrc/wdst = W2 @ a_src2 / W2 @ a_dst2  (64 each) ----------------
__global__ __launch_bounds__(128) void k_wvec(const float* __restrict__ W2,
    const float* __restrict__ a_src2, const float* __restrict__ a_dst2,
    float* __restrict__ wsrc, float* __restrict__ wdst)
{
    int t = threadIdx.x;
    int k = t & 63;
    const float* a = (t < 64) ? a_src2 : a_dst2;
    float s = 0.f;
    for (int c = 0; c < D2; ++c) s = fmaf(W2[k * D2 + c], a[c], s);
    if (t < 64) wsrc[k] = s; else wdst[k] = s;
}

// ---------------- CSR build: binned path (N <= 2^17) ----------------
__global__ __launch_bounds__(256) void k_binhist(const int* __restrict__ ei, int E, int N,
    int nbins, int* __restrict__ binCnt)
{
    __shared__ int lcnt[1024];
    int tot = E + N;
    int t0 = blockIdx.x * TILEB;
    int cnt = min(TILEB, tot - t0);
    for (int i = threadIdx.x; i < nbins; i += 256) lcnt[i] = 0;
    __syncthreads();
    for (int i = threadIdx.x; i < cnt; i += 256) {
        int e = t0 + i;
        int dst = (e < E) ? ei[(size_t)E + e] : (e - E);
        atomicAdd(&lcnt[dst >> 7], 1);
    }
    __syncthreads();
    for (int i = threadIdx.x; i < nbins; i += 256)
        if (lcnt[i]) atomicAdd(&binCnt[i], lcnt[i]);
}

__global__ __launch_bounds__(256) void k_binscan(const int* __restrict__ binCnt,
    int* __restrict__ binOff, int* __restrict__ binCur, int nbins)
{
    __shared__ int wtot[4];
    int t = threadIdx.x, lane = t & 63, wave = t >> 6;
    int v[4];
    #pragma unroll
    for (int j = 0; j < 4; ++j) {
        int idx = t * 4 + j;
        v[j] = (idx < nbins) ? binCnt[idx] : 0;
    }
    int s = v[0] + v[1] + v[2] + v[3];
    int incl = s;
    #pragma unroll
    for (int off = 1; off < 64; off <<= 1) {
        int tt = __shfl_up(incl, off);
        if (lane >= off) incl += tt;
    }
    if (lane == 63) wtot[wave] = incl;
    __syncthreads();
    int woff = 0;
    #pragma unroll
    for (int w = 0; w < 4; ++w) if (w < wave) woff += wtot[w];
    int run = woff + incl - s;
    #pragma unroll
    for (int j = 0; j < 4; ++j) {
        int idx = t * 4 + j;
        if (idx < nbins) { binOff[idx] = run; binCur[idx] = run; }
        run += v[j];
    }
    if (t == 255) binOff[nbins] = woff + incl;
}

__global__ __launch_bounds__(256) void k_bin(const int* __restrict__ ei, int E, int N,
    int nbins, int* __restrict__ binCur, int* __restrict__ binned)
{
    __shared__ int recs[TILEB];
    __shared__ unsigned short bns[TILEB];
    __shared__ int lcnt[1024];
    __shared__ int lbase[1024];
    int tot = E + N;
    int t0 = blockIdx.x * TILEB;
    int cnt = min(TILEB, tot - t0);
    for (int i = threadIdx.x; i < nbins; i += 256) lcnt[i] = 0;
    __syncthreads();
    for (int i = threadIdx.x; i < cnt; i += 256) {
        int e = t0 + i;
        int src, dst;
        if (e < E) { src = ei[e]; dst = ei[(size_t)E + e]; }
        else       { src = e - E; dst = src; }
        int b = dst >> 7;
        recs[i] = src | ((dst & 127) << 17);
        bns[i] = (unsigned short)b;
        atomicAdd(&lcnt[b], 1);
    }
    __syncthreads();
    for (int i = threadIdx.x; i < nbins; i += 256) {
        int c = lcnt[i];
        if (c) lbase[i] = atomicAdd(&binCur[i], c);
        lcnt[i] = 0;
    }
    __syncthreads();
    for (int i = threadIdx.x; i < cnt; i += 256) {
        int b = bns[i];
        int lp = atomicAdd(&lcnt[b], 1);
        binned[lbase[b] + lp] = recs[i];
    }
}

__global__ __launch_bounds__(256) void k_bindeg(const int* __restrict__ binOff,
    const int* __restrict__ binned, int* __restrict__ deg, int N)
{
    __shared__ int cnt[NPBIN];
    int b = blockIdx.x;
    int s0 = binOff[b], s1 = binOff[b + 1];
    if (threadIdx.x < NPBIN) cnt[threadIdx.x] = 0;
    __syncthreads();
    for (int i = s0 + threadIdx.x; i < s1; i += 256)
        atomicAdd(&cnt[binned[i] >> 17], 1);
    __syncthreads();
    int node = b * NPBIN + threadIdx.x;
    if (threadIdx.x < NPBIN && node < N) deg[node] = cnt[threadIdx.x];
}

__global__ __launch_bounds__(256) void k_binscatter(const int* __restrict__ binOff,
    const int* __restrict__ binned, const int* __restrict__ ptr,
    int* __restrict__ edge_src, int N)
{
    __shared__ int cur[NPBIN];
    int b = blockIdx.x;
    int base = b * NPBIN;
    if (threadIdx.x < NPBIN) {
        int node = base + threadIdx.x;
        cur[threadIdx.x] = (node < N) ? ptr[node] : 0;
    }
    __syncthreads();
    int s0 = binOff[b], s1 = binOff[b + 1];
    for (int i = s0 + threadIdx.x; i < s1; i += 256) {
        int rec = binned[i];
        int p = atomicAdd(&cur[rec >> 17], 1);
        edge_src[p] = rec & 0x1FFFF;
    }
}

// ---------------- CSR build: fallback path ----------------
__global__ void k_count(const int* __restrict__ ei, int E, int N,
                        int* __restrict__ deg)
{
    int tot = E + N;
    for (int e = blockIdx.x * blockDim.x + threadIdx.x; e < tot;
         e += gridDim.x * blockDim.x) {
        int dst = (e < E) ? ei[(size_t)E + e] : (e - E);
        atomicAdd(&deg[dst], 1);
    }
}

__global__ void k_scatter(const int* __restrict__ ei, int E, int N,
                          int* __restrict__ cursor, int* __restrict__ edge_src)
{
    int tot = E + N;
    for (int e = blockIdx.x * blockDim.x + threadIdx.x; e < tot;
         e += gridDim.x * blockDim.x) {
        int src, dst;
        if (e < E) { src = ei[e]; dst = ei[(size_t)E + e]; }
        else       { src = e - E; dst = e - E; }
        int pos = atomicAdd(&cursor[dst], 1);
        edge_src[pos] = src;
    }
}

// ---------------- deg scan ----------------
__global__ __launch_bounds__(256) void k_scanA(const int* __restrict__ deg,
    int* __restrict__ ptr, int* __restrict__ chunkSum)
{
    __shared__ int wtot[4];
    int b = blockIdx.x, t = threadIdx.x;
    int lane = t & 63, wave = t >> 6;
    int4 v = reinterpret_cast<const int4*>(deg + (size_t)b * CH)[t];
    int s = v.x + v.y + v.z + v.w;
    int incl = s;
    #pragma unroll
    for (int off = 1; off < 64; off <<= 1) {
        int tt = __shfl_up(incl, off);
        if (lane >= off) incl += tt;
    }
    if (lane == 63) wtot[wave] = incl;
    __syncthreads();
    int woff = 0;
    #pragma unroll
    for (int w = 0; w < 4; ++w) if (w < wave) woff += wtot[w];
    int excl = woff + incl - s;
    int i0 = b * CH + t * 4;
    ptr[i0 + 0] = excl;
    ptr[i0 + 1] = excl + v.x;
    ptr[i0 + 2] = excl + v.x + v.y;
    ptr[i0 + 3] = excl + v.x + v.y + v.z;
    if (t == 255) chunkSum[b] = woff + incl;
}

__global__ void k_scanB(const int* __restrict__ chunkSum, int* __restrict__ chunkOff,
                        int NB, int* __restrict__ ptrN)
{
    if (threadIdx.x == 0) {
        int c = 0;
        for (int b = 0; b < NB; ++b) { chunkOff[b] = c; c += chunkSum[b]; }
        *ptrN = c;
    }
}

__global__ __launch_bounds__(256) void k_scanC(int* __restrict__ ptr,
    int* __restrict__ cursor, const int* __restrict__ chunkOff, int N)
{
    int b = blockIdx.x;
    int off = chunkOff[b];
    int i0 = b * CH + threadIdx.x * 4;
    #pragma unroll
    for (int k = 0; k < 4; ++k) {
        int i = i0 + k;
        if (i < N) { int v = ptr[i] + off; ptr[i] = v; cursor[i] = v; }
    }
}

// -------- Layer-1 aggregation: two-phase softmax (exp once per edge-head) --------
// Phase 1: lanes = 8 edges x 8 heads; ev->LDS stash; shfl-reduce max+sum.
// Phase 2: pure LDS-broadcast x h1-row-gather fma, 8-deep MLP.
template<typename T>
__global__ __launch_bounds__(256) void k_agg1(const int* __restrict__ ptr,
    const int* __restrict__ edge_src, const T* __restrict__ h1,
    const float* __restrict__ asrc1, const float* __restrict__ adst1,
    const float* __restrict__ b1, const float* __restrict__ wsrc,
    const float* __restrict__ wdst, T* __restrict__ hmid,
    float* __restrict__ asrc2, float* __restrict__ adst2, int N)
{
    __shared__ float S1[4 * MAXD1 * H1];           // 16 KB per-wave stash
    int wave = threadIdx.x >> 6, lane = threadIdx.x & 63;
    float* st = S1 + wave * (MAXD1 * H1);
    int n = blockIdx.x * 4 + wave;
    if (n >= N) return;
    int start = ptr[n], end = ptr[n + 1];
    int deg = end - start;
    int h = lane >> 3;
    float o;

    if (deg <= MAXD1) {
        // ---- phase 1 ----
        int e_loc = lane >> 3, hh = lane & 7;
        float adsth = adst1[n * H1 + hh];
        float mloc = -1e30f;
        for (int eb = start, base = 0; eb < end; eb += 8, base += 64) {
            int e = eb + e_loc;
            float ev = -1e30f;
            if (e < end) {
                int s = edge_src[e];
                ev = asrc1[s * H1 + hh] + adsth;
                ev = ev > 0.f ? ev : NEG * ev;
                st[base + lane] = ev;
            }
            mloc = fmaxf(mloc, ev);
        }
        mloc = fmaxf(mloc, __shfl_xor(mloc, 8));
        mloc = fmaxf(mloc, __shfl_xor(mloc, 16));
        mloc = fmaxf(mloc, __shfl_xor(mloc, 32));
        __builtin_amdgcn_wave_barrier();
        float sloc = 0.f;
        for (int eb = start, base = 0; eb < end; eb += 8, base += 64) {
            if (eb + e_loc < end) {
                float p = __expf(st[base + lane] - mloc);
                st[base + lane] = p;
                sloc += p;
            }
        }
        sloc += __shfl_xor(sloc, 8);
        sloc += __shfl_xor(sloc, 16);
        sloc += __shfl_xor(sloc, 32);
        float inv = 1.f / (sloc + EPSS);
        __builtin_amdgcn_wave_barrier();
        float inv_c = __shfl(inv, h);               // head-layout -> channel-layout

        // ---- phase 2: 8-deep independent gathers ----
        float a0 = 0.f, a1 = 0.f, a2 = 0.f, a3 = 0.f;
        float a4 = 0.f, a5 = 0.f, a6 = 0.f, a7 = 0.f;
        int e = start;
        for (; e + 8 <= end; e += 8) {
            int r = e - start;
            int i0 = edge_src[e + 0]; int i1 = edge_src[e + 1];
            int i2 = edge_src[e + 2]; int i3 = edge_src[e + 3];
            int i4 = edge_src[e + 4]; int i5 = edge_src[e + 5];
            int i6 = edge_src[e + 6]; int i7 = edge_src[e + 7];
            float w0 = st[(r + 0) * H1 + h]; float w1 = st[(r + 1) * H1 + h];
            float w2 = st[(r + 2) * H1 + h]; float w3 = st[(r + 3) * H1 + h];
            float w4 = st[(r + 4) * H1 + h]; float w5 = st[(r + 5) * H1 + h];
            float w6 = st[(r + 6) * H1 + h]; float w7 = st[(r + 7) * H1 + h];
            a0 = fmaf(w0, toF(h1[((size_t)(unsigned)i0 << 6) + lane]), a0);
            a1 = fmaf(w1, toF(h1[((size_t)(unsigned)i1 << 6) + lane]), a1);
            a2 = fmaf(w2, toF(h1[((size_t)(unsigned)i2 << 6) + lane]), a2);
            a3 = fmaf(w3, toF(h1[((size_t)(unsigned)i3 << 6) + lane]), a3);
            a4 = fmaf(w4, toF(h1[((size_t)(unsigned)i4 << 6) + lane]), a4);
            a5 = fmaf(w5, toF(h1[((size_t)(unsigned)i5 << 6) + lane]), a5);
            a6 = fmaf(w6, toF(h1[((size_t)(unsigned)i6 << 6) + lane]), a6);
            a7 = fmaf(w7, toF(h1[((size_t)(unsigned)i7 << 6) + lane]), a7);
        }
        for (; e < end; ++e) {
            int s = edge_src[e];
            a0 = fmaf(st[(e - start) * H1 + h],
                      toF(h1[((size_t)(unsigned)s << 6) + lane]), a0);
        }
        float acc = ((a0 + a1) + (a2 + a3)) + ((a4 + a5) + (a6 + a7));
        o = acc * inv_c;
    } else {
        // ---- fallback: 8-chain online softmax ----
        float adst = adst1[n * H1 + h];
        float m[8], ss[8], aa[8];
        #pragma unroll
        for (int j = 0; j < 8; ++j) { m[j] = -1e30f; ss[j] = 0.f; aa[j] = 0.f; }
        int e = start;
        for (; e + 8 <= end; e += 8) {
            int idx[8];
            #pragma unroll
            for (int j = 0; j < 8; ++j) idx[j] = edge_src[e + j];
            #pragma unroll
            for (int j = 0; j < 8; ++j) {
                float t = asrc1[idx[j] * H1 + h] + adst;
                t = t > 0.f ? t : NEG * t;
                chain_upd(t, toF(h1[((size_t)(unsigned)idx[j] << 6) + lane]),
                          m[j], ss[j], aa[j]);
            }
        }
        for (; e < end; ++e) {
            int s = edge_src[e];
            float t = asrc1[s * H1 + h] + adst;
            t = t > 0.f ? t : NEG * t;
            chain_upd(t, toF(h1[((size_t)(unsigned)s << 6) + lane]), m[0], ss[0], aa[0]);
        }
        float M = fmaxf(fmaxf(fmaxf(m[0], m[1]), fmaxf(m[2], m[3])),
                        fmaxf(fmaxf(m[4], m[5]), fmaxf(m[6], m[7])));
        float sum = 0.f, acc = 0.f;
        #pragma unroll
        for (int j = 0; j < 8; ++j) {
            float sc = __expf(m[j] - M);
            sum = fmaf(ss[j], sc, sum);
            acc = fmaf(aa[j], sc, acc);
        }
        o = acc / (sum + EPSS);
    }

    o = o + b1[lane];
    o = o > 0.f ? o : (expf(o) - 1.f);   // ELU
    hmid[(size_t)n * C1 + lane] = fromF<T>(o);
    float vs = o * wsrc[lane];
    float vd = o * wdst[lane];
    #pragma unroll
    for (int off = 1; off < 64; off <<= 1) {
        vs += __shfl_xor(vs, off);
        vd += __shfl_xor(vd, off);
    }
    if (lane == 0) { asrc2[n] = vs; adst2[n] = vd; }
}

// ------ Layer-2 aggregation: two-phase softmax; writes aggv ------
template<typename T>
__global__ __launch_bounds__(256) void k_agg2(const int* __restrict__ ptr,
    const int* __restrict__ edge_src, const T* __restrict__ hmid,
    const float* __restrict__ asrc2, const float* __restrict__ adst2,
    T* __restrict__ aggv_out, int N)
{
    __shared__ float S2[4 * MAXD2];                // 4 KB per-wave stash
    int wave = threadIdx.x >> 6, lane = threadIdx.x & 63;
    float* st = S2 + wave * MAXD2;
    int n = blockIdx.x * 4 + wave;
    if (n >= N) return;
    int start = ptr[n], end = ptr[n + 1];
    int deg = end - start;
    float adst = adst2[n];
    float aggv;

    if (deg <= MAXD2) {
        // ---- phase 1: lanes over edges ----
        float mloc = -1e30f;
        for (int e = start + lane; e < end; e += 64) {
            int s = edge_src[e];
            float ev = asrc2[s] + adst;
            ev = ev > 0.f ? ev : NEG * ev;
            st[e - start] = ev;
            mloc = fmaxf(mloc, ev);
        }
        #pragma unroll
        for (int off = 1; off < 64; off <<= 1)
            mloc = fmaxf(mloc, __shfl_xor(mloc, off));
        __builtin_amdgcn_wave_barrier();
        float sloc = 0.f;
        for (int e = start + lane; e < end; e += 64) {
            float p = __expf(st[e - start] - mloc);
            st[e - start] = p;
            sloc += p;
        }
        #pragma unroll
        for (int off = 1; off < 64; off <<= 1)
            sloc += __shfl_xor(sloc, off);
        float inv = 1.f / (sloc + EPSS);
        __builtin_amdgcn_wave_barrier();

        // ---- phase 2: 8-deep independent gathers ----
        float a0 = 0.f, a1 = 0.f, a2 = 0.f, a3 = 0.f;
        float a4 = 0.f, a5 = 0.f, a6 = 0.f, a7 = 0.f;
        int e = start;
        for (; e + 8 <= end; e += 8) {
            int r = e - start;
            int i0 = edge_src[e + 0]; int i1 = edge_src[e + 1];
            int i2 = edge_src[e + 2]; int i3 = edge_src[e + 3];
            int i4 = edge_src[e + 4]; int i5 = edge_src[e + 5];
            int i6 = edge_src[e + 6]; int i7 = edge_src[e + 7];
            a0 = fmaf(st[r + 0], toF(hmid[((size_t)(unsigned)i0 << 6) + lane]), a0);
            a1 = fmaf(st[r + 1], toF(hmid[((size_t)(unsigned)i1 << 6) + lane]), a1);
            a2 = fmaf(st[r + 2], toF(hmid[((size_t)(unsigned)i2 << 6) + lane]), a2);
            a3 = fmaf(st[r + 3], toF(hmid[((size_t)(unsigned)i3 << 6) + lane]), a3);
            a4 = fmaf(st[r + 4], toF(hmid[((size_t)(unsigned)i4 << 6) + lane]), a4);
            a5 = fmaf(st[r + 5], toF(hmid[((size_t)(unsigned)i5 << 6) + lane]), a5);
            a6 = fmaf(st[r + 6], toF(hmid[((size_t)(unsigned)i6 << 6) + lane]), a6);
            a7 = fmaf(st[r + 7], toF(hmid[((size_t)(unsigned)i7 << 6) + lane]), a7);
        }
        for (; e < end; ++e) {
            int s = edge_src[e];
            a0 = fmaf(st[e - start], toF(hmid[((size_t)(unsigned)s << 6) + lane]), a0);
        }
        float acc = ((a0 + a1) + (a2 + a3)) + ((a4 + a5) + (a6 + a7));
        aggv = acc * inv;
    } else {
        // ---- fallback: 8-chain online softmax ----
        float m[8], ss[8], aa[8];
        #pragma unroll
        for (int j = 0; j < 8; ++j) { m[j] = -1e30f; ss[j] = 0.f; aa[j] = 0.f; }
        int e = start;
        for (; e + 8 <= end; e += 8) {
            int idx[8];
            #pragma unroll
            for (int j = 0; j < 8; ++j) idx[j] = edge_src[e + j];
            #pragma unroll
            for (int j = 0; j < 8; ++j) {
                float t = asrc2[idx[j]] + adst;
                t = t > 0.f ? t : NEG * t;
                chain_upd(t, toF(hmid[((size_t)(unsigned)idx[j] << 6) + lane]),
                          m[j], ss[j], aa[j]);
            }
        }
        for (; e < end; ++e) {
            int s = edge_src[e];
            float t = asrc2[s] + adst;
            t = t > 0.f ? t : NEG * t;
            chain_upd(t, toF(hmid[((size_t)(unsigned)s << 6) + lane]), m[0], ss[0], aa[0]);
        }
        float M = fmaxf(fmaxf(fmaxf(m[0], m[1]), fmaxf(m[2], m[3])),
                        fmaxf(fmaxf(m[4], m[5]), fmaxf(m[6], m[7])));
        float sum = 0.f, acc = 0.f;
        #pragma unroll
        for (int j = 0; j < 8; ++j) {
            float sc = __expf(m[j] - M);
            sum = fmaf(ss[j], sc, sum);
            acc = fmaf(aa[j], sc, acc);
        }
        aggv = acc / (sum + EPSS);
    }
    aggv_out[(size_t)n * C1 + lane] = fromF<T>(aggv);
}

// ---------------- GEMM2: out = aggv @ W2 + b2 (dense, streaming) ----------------
template<typename T>
__global__ __launch_bounds__(256) void k_gemm2(const T* __restrict__ aggv,
    const float* __restrict__ W2, const float* __restrict__ b2,
    float* __restrict__ out, int N)
{
    __shared__ float Ws[C1 * D2];                  // 32 KB
    for (int i = threadIdx.x; i < C1 * D2 / 4; i += 256)
        reinterpret_cast<float4*>(Ws)[i] = reinterpret_cast<const float4*>(W2)[i];

    int wave = threadIdx.x >> 6, lane = threadIdx.x & 63;
    int n0 = blockIdx.x * NPB2 + wave * NPW2;

    float av[NPW2];
    #pragma unroll
    for (int j = 0; j < NPW2; ++j) {
        int n = n0 + j;
        av[j] = (n < N) ? toF(aggv[(size_t)n * C1 + lane]) : 0.f;
    }
    __syncthreads();

    float acc0[NPW2], acc1[NPW2];
    #pragma unroll
    for (int j = 0; j < NPW2; ++j) { acc0[j] = 0.f; acc1[j] = 0.f; }

    #pragma unroll 4
    for (int k = 0; k < 64; ++k) {
        float w0 = Ws[k * D2 + lane];
        float w1 = Ws[k * D2 + 64 + lane];
        #pragma unroll
        for (int j = 0; j < NPW2; ++j) {
            float xk = bcast_lane(av[j], k);
            acc0[j] = fmaf(xk, w0, acc0[j]);
            acc1[j] = fmaf(xk, w1, acc1[j]);
        }
    }

    float bb0 = b2[lane], bb1 = b2[64 + lane];
    #pragma unroll
    for (int j = 0; j < NPW2; ++j) {
        int n = n0 + j;
        if (n >= N) continue;
        out[(size_t)n * D2 + lane]      = acc0[j] + bb0;
        out[(size_t)n * D2 + 64 + lane] = acc1[j] + bb1;
    }
}

extern "C" void kernel_launch(void* const* d_in, const int* in_sizes, int n_in,
                              void* d_out, int out_size, void* d_ws, size_t ws_size,
                              hipStream_t stream)
{
    const float* x      = (const float*)d_in[0];
    const int*   ei     = (const int*)d_in[1];
    const float* W1     = (const float*)d_in[2];
    const float* a_src1 = (const float*)d_in[3];
    const float* a_dst1 = (const float*)d_in[4];
    const float* b1     = (const float*)d_in[5];
    const float* W2     = (const float*)d_in[6];
    const float* a_src2 = (const float*)d_in[7];
    const float* a_dst2 = (const float*)d_in[8];
    const float* b2     = (const float*)d_in[9];
    float* out = (float*)d_out;

    const int N = in_sizes[0] / FIN;
    const int E = in_sizes[1] / 2;
    const int Etot = E + N;
    const int NB = (N + CH - 1) / CH;     // scan chunks
    const size_t NP = (size_t)NB * CH;    // padded node count

    const size_t common =
        ((size_t)N * H1 * 4 + 255 & ~(size_t)255) * 2 +   // asrc1, adst1
        (((size_t)N * 4 + 255) & ~(size_t)255) * 2 +       // asrc2, adst2
        512 +                                              // wsrc, wdst
        (((size_t)NP * 4 + 255) & ~(size_t)255) * 2 +      // deg, cursor
        (((size_t)(NP + 1) * 4 + 255) & ~(size_t)255) +    // ptr
        (((size_t)NB * 4 + 255) & ~(size_t)255) * 2 +      // chunkSum, chunkOff
        (((size_t)Etot * 4 + 255) & ~(size_t)255) +        // edge_src
        4096;                                              // slack
    const bool f32path = ws_size >= common + 2 * ((size_t)N * C1 * 4 + 256);

    char* ws = (char*)d_ws;
    size_t off = 0;
    auto alloc = [&](size_t bytes) -> void* {
        void* p = ws + off;
        off = (off + bytes + 255) & ~(size_t)255;
        return p;
    };
    const size_t es = f32path ? 4 : 2;
    void*  h1v    = alloc((size_t)N * C1 * es);   // aliased: binned CSR records, later aggv
    void*  hmidv  = alloc((size_t)N * C1 * es);   // aliased: bin control arrays during CSR
    float* asrc1  = (float*)alloc((size_t)N * H1 * 4);
    float* adst1  = (float*)alloc((size_t)N * H1 * 4);
    float* asrc2  = (float*)alloc((size_t)N * 4);
    float* adst2  = (float*)alloc((size_t)N * 4);
    float* wsrc   = (float*)alloc(64 * 4);
    float* wdst   = (float*)alloc(64 * 4);
    int*   deg    = (int*)alloc(NP * 4);
    int*   ptr    = (int*)alloc((NP + 1) * 4);
    int*   cursor = (int*)alloc(NP * 4);
    int*   chunkSum = (int*)alloc((size_t)NB * 4);
    int*   chunkOff = (int*)alloc((size_t)NB * 4);
    int*   edge_src = (int*)alloc((size_t)Etot * 4);

    const int nodeBlocks = (N + 3) / 4;
    const int g1Blocks = (N + 63) / 64;
    const int g2Blocks = (N + NPB2 - 1) / NPB2;

    // ---- CSR build (dst-indexed) ----
    const int nbins = (N + NPBIN - 1) / NPBIN;
    const bool binpath = (N <= (1 << 17)) &&
                         ((size_t)Etot * 4 <= (size_t)N * C1 * es);
    hipMemsetAsync(deg, 0, NP * 4, stream);
    if (binpath) {
        int* binned = (int*)h1v;                   // Etot ints
        int* binCnt = (int*)hmidv;                 // nbins
        int* binOff = binCnt + 1056;               // nbins+1
        int* binCur = binOff + 1056;               // nbins
        const int binBlocks = (Etot + TILEB - 1) / TILEB;
        hipMemsetAsync(binCnt, 0, (size_t)nbins * 4, stream);
        k_binhist<<<binBlocks, 256, 0, stream>>>(ei, E, N, nbins, binCnt);
        k_binscan<<<1, 256, 0, stream>>>(binCnt, binOff, binCur, nbins);
        k_bin<<<binBlocks, 256, 0, stream>>>(ei, E, N, nbins, binCur, binned);
        k_bindeg<<<nbins, 256, 0, stream>>>(binOff, binned, deg, N);
        k_scanA<<<NB, 256, 0, stream>>>(deg, ptr, chunkSum);
        k_scanB<<<1, 64, 0, stream>>>(chunkSum, chunkOff, NB, ptr + N);
        k_scanC<<<NB, 256, 0, stream>>>(ptr, cursor, chunkOff, N);
        k_binscatter<<<nbins, 256, 0, stream>>>(binOff, binned, ptr, edge_src, N);
    } else {
        k_count<<<2048, 256, 0, stream>>>(ei, E, N, deg);
        k_scanA<<<NB, 256, 0, stream>>>(deg, ptr, chunkSum);
        k_scanB<<<1, 64, 0, stream>>>(chunkSum, chunkOff, NB, ptr + N);
        k_scanC<<<NB, 256, 0, stream>>>(ptr, cursor, chunkOff, N);
        k_scatter<<<2048, 256, 0, stream>>>(ei, E, N, cursor, edge_src);
    }

    k_wvec<<<1, 128, 0, stream>>>(W2, a_src2, a_dst2, wsrc, wdst);

    if (f32path) {
        float* h1 = (float*)h1v; float* hmid = (float*)hmidv;
        k_gemm1<float><<<g1Blocks, 256, 0, stream>>>(x, W1, a_src1, a_dst1, h1, asrc1, adst1, N);
        k_agg1<float><<<nodeBlocks, 256, 0, stream>>>(ptr, edge_src, h1, asrc1, adst1, b1,
                                                      wsrc, wdst, hmid, asrc2, adst2, N);
        float* aggv = (float*)h1v;   // h1 dead after agg1
        k_agg2<float><<<nodeBlocks, 256, 0, stream>>>(ptr, edge_src, hmid, asrc2, adst2, aggv, N);
        k_gemm2<float><<<g2Blocks, 256, 0, stream>>>(aggv, W2, b2, out, N);
    } else {
        __hip_bfloat16* h1 = (__hip_bfloat16*)h1v; __hip_bfloat16* hmid = (__hip_bfloat16*)hmidv;
        k_gemm1<__hip_bfloat16><<<g1Blocks, 256, 0, stream>>>(x, W1, a_src1, a_dst1, h1, asrc1, adst1, N);
        k_agg1<__hip_bfloat16><<<nodeBlocks, 256, 0, stream>>>(ptr, edge_src, h1, asrc1, adst1, b1,
                                                               wsrc, wdst, hmid, asrc2, adst2, N);
        __hip_bfloat16* aggv = (__hip_bfloat16*)h1v;   // h1 dead after agg1
        k_agg2<__hip_bfloat16><<<nodeBlocks, 256, 0, stream>>>(ptr, edge_src, hmid, asrc2, adst2, aggv, N);
        k_gemm2<__hip_bfloat16><<<g2Blocks, 256, 0, stream>>>(aggv, W2, b2, out, N);
    }
}

// Round 8
// 358.874 us; speedup vs baseline: 1.0344x; 1.0344x over previous
//
#include <hip/hip_runtime.h>
#include <hip/hip_bf16.h>
#include <cstdint>

#define H1 8
#define C1 64      // H1*D1
#define D2 128
#define FIN 256
#define NEG 0.2f
#define EPSS 1e-16f
#define CH 1024    // nodes per scan chunk
#define NPW2 8     // gemm2: nodes per wave
#define NPB2 32    // gemm2: nodes per block
#define XPAD 264   // gemm1 LDS row stride in bf16
#define HP 68      // gemm1 epilogue f32 row stride
#define NPBIN 128  // nodes per bin (CSR binning)
#define TILEB 4096 // edges per k_bin block
#define MAXD1 128  // agg1 fast-path degree cap
#define MAXD2 256  // agg2 fast-path degree cap

template<typename T> __device__ __forceinline__ float toF(T v);
template<> __device__ __forceinline__ float toF<float>(float v) { return v; }
template<> __device__ __forceinline__ float toF<__hip_bfloat16>(__hip_bfloat16 v) { return __bfloat162float(v); }
template<typename T> __device__ __forceinline__ T fromF(float v);
template<> __device__ __forceinline__ float fromF<float>(float v) { return v; }
template<> __device__ __forceinline__ __hip_bfloat16 fromF<__hip_bfloat16>(float v) { return __float2bfloat16(v); }

__device__ __forceinline__ float bcast_lane(float v, int lane) {
    return __int_as_float(__builtin_amdgcn_readlane(__float_as_int(v), lane));
}

__device__ __forceinline__ unsigned pk_bf16(float lo, float hi) {
    unsigned a = (unsigned)__bfloat16_as_ushort(__float2bfloat16(lo));
    unsigned b = (unsigned)__bfloat16_as_ushort(__float2bfloat16(hi));
    return a | (b << 16);
}

typedef __attribute__((ext_vector_type(8))) short bf16x8;
typedef __attribute__((ext_vector_type(4))) float f32x4;

// online-softmax chain update (fallback path)
__device__ __forceinline__ void chain_upd(float ev, float hv,
                                          float& m, float& s, float& a)
{
    float mn = fmaxf(m, ev);
    float sc = __expf(m - mn);
    float p  = __expf(ev - mn);
    s = fmaf(s, sc, p);
    a = fmaf(a, sc, p * hv);
    m = mn;
}

// ---------------- GEMM1 (MFMA): h1 = x @ W1, fused alpha_src1/alpha_dst1 ----------------
template<typename T>
__global__ __launch_bounds__(256) void k_gemm1(const float* __restrict__ x,
    const float* __restrict__ W1, const float* __restrict__ a_src1,
    const float* __restrict__ a_dst1, T* __restrict__ h1,
    float* __restrict__ asrc1, float* __restrict__ adst1, int N)
{
    __shared__ alignas(16) unsigned short Xs[64 * XPAD];   // 33.8 KB (reused as f32 Hs)
    __shared__ alignas(16) unsigned short Wt[64 * XPAD];   // 33.8 KB: Wt[col][k]
    int tid = threadIdx.x;
    int wave = tid >> 6, lane = tid & 63;
    int nodeBase = blockIdx.x * 64;

    // stage W1^T bf16
    {
        int c = tid & 63;
        int kb = (tid >> 6) * 4;
        #pragma unroll
        for (int s = 0; s < 16; ++s) {
            int k0 = s * 16 + kb;
            float f0 = W1[(k0 + 0) * C1 + c];
            float f1 = W1[(k0 + 1) * C1 + c];
            float f2 = W1[(k0 + 2) * C1 + c];
            float f3 = W1[(k0 + 3) * C1 + c];
            *reinterpret_cast<uint2*>(&Wt[c * XPAD + k0]) =
                make_uint2(pk_bf16(f0, f1), pk_bf16(f2, f3));
        }
    }
    // stage x tile bf16
    for (int i = tid; i < 64 * 64; i += 256) {
        int r = i >> 6, kq = i & 63;
        int n = nodeBase + r;
        float4 v = (n < N) ? reinterpret_cast<const float4*>(x)[(size_t)n * 64 + kq]
                           : make_float4(0.f, 0.f, 0.f, 0.f);
        *reinterpret_cast<uint2*>(&Xs[r * XPAD + kq * 4]) =
            make_uint2(pk_bf16(v.x, v.y), pk_bf16(v.z, v.w));
    }
    __syncthreads();

    int m = lane & 15;
    int kg = lane >> 4;
    int arow = wave * 16 + m;
    f32x4 acc[4];
    #pragma unroll
    for (int t = 0; t < 4; ++t) acc[t] = (f32x4){0.f, 0.f, 0.f, 0.f};
    #pragma unroll
    for (int ks = 0; ks < 8; ++ks) {
        int k0 = ks * 32 + kg * 8;
        bf16x8 a = *reinterpret_cast<const bf16x8*>(&Xs[arow * XPAD + k0]);
        #pragma unroll
        for (int t = 0; t < 4; ++t) {
            bf16x8 b = *reinterpret_cast<const bf16x8*>(&Wt[(t * 16 + m) * XPAD + k0]);
            acc[t] = __builtin_amdgcn_mfma_f32_16x16x32_bf16(a, b, acc[t], 0, 0, 0);
        }
    }
    __syncthreads();

    float* Hs = reinterpret_cast<float*>(Xs);
    int crow = (lane >> 4) * 4;
    #pragma unroll
    for (int t = 0; t < 4; ++t)
        #pragma unroll
        for (int r = 0; r < 4; ++r)
            Hs[(wave * 16 + crow + r) * HP + t * 16 + m] = acc[t][r];
    __syncthreads();

    float as_l = a_src1[lane], ad_l = a_dst1[lane];
    int n0 = nodeBase + wave * 16;
    #pragma unroll
    for (int i = 0; i < 16; ++i) {
        int n = n0 + i;
        if (n >= N) break;
        float hv = Hs[(wave * 16 + i) * HP + lane];
        h1[(size_t)n * C1 + lane] = fromF<T>(hv);
        float vs = hv * as_l, vd = hv * ad_l;
        #pragma unroll
        for (int off = 1; off < 8; off <<= 1) {
            vs += __shfl_xor(vs, off);
            vd += __shfl_xor(vd, off);
        }
        if ((lane & 7) == 0) {
            asrc1[n * H1 + (lane >> 3)] = vs;
            adst1[n * H1 + (lane >> 3)] = vd;
        }
    }
}

// ---------------- wsrc/wdst = W2 @ a_src2 / W2 @ a_dst2  (64 each) ----------------
__global__ __launch_bounds__(128) void k_wvec(const float* __restrict__ W2,
    const float* __restrict__ a_src2, const float* __restrict__ a_dst2,
    float* __restrict__ wsrc, float* __restrict__ wdst)
{
    int t = threadIdx.x;
    int k = t & 63;
    const float* a = (t < 64) ? a_src2 : a_dst2;
    float s = 0.f;
    for (int c = 0; c < D2; ++c) s = fmaf(W2[k * D2 + c], a[c], s);
    if (t < 64) wsrc[k] = s; else wdst[k] = s;
}

// ---------------- CSR build: binned path (N <= 2^17) ----------------
__global__ __launch_bounds__(256) void k_binhist(const int* __restrict__ ei, int E, int N,
    int nbins, int* __restrict__ binCnt)
{
    __shared__ int lcnt[1024];
    int tot = E + N;
    int t0 = blockIdx.x * TILEB;
    int cnt = min(TILEB, tot - t0);
    for (int i = threadIdx.x; i < nbins; i += 256) lcnt[i] = 0;
    __syncthreads();
    for (int i = threadIdx.x; i < cnt; i += 256) {
        int e = t0 + i;
        int dst = (e < E) ? ei[(size_t)E + e] : (e - E);
        atomicAdd(&lcnt[dst >> 7], 1);
    }
    __syncthreads();
    for (int i = threadIdx.x; i < nbins; i += 256)
        if (lcnt[i]) atomicAdd(&binCnt[i], lcnt[i]);
}

__global__ __launch_bounds__(256) void k_binscan(const int* __restrict__ binCnt,
    int* __restrict__ binOff, int* __restrict__ binCur, int nbins)
{
    __shared__ int wtot[4];
    int t = threadIdx.x, lane = t & 63, wave = t >> 6;
    int v[4];
    #pragma unroll
    for (int j = 0; j < 4; ++j) {
        int idx = t * 4 + j;
        v[j] = (idx < nbins) ? binCnt[idx] : 0;
    }
    int s = v[0] + v[1] + v[2] + v[3];
    int incl = s;
    #pragma unroll
    for (int off = 1; off < 64; off <<= 1) {
        int tt = __shfl_up(incl, off);
        if (lane >= off) incl += tt;
    }
    if (lane == 63) wtot[wave] = incl;
    __syncthreads();
    int woff = 0;
    #pragma unroll
    for (int w = 0; w < 4; ++w) if (w < wave) woff += wtot[w];
    int run = woff + incl - s;
    #pragma unroll
    for (int j = 0; j < 4; ++j) {
        int idx = t * 4 + j;
        if (idx < nbins) { binOff[idx] = run; binCur[idx] = run; }
        run += v[j];
    }
    if (t == 255) binOff[nbins] = woff + incl;
}

__global__ __launch_bounds__(256) void k_bin(const int* __restrict__ ei, int E, int N,
    int nbins, int* __restrict__ binCur, int* __restrict__ binned)
{
    __shared__ int recs[TILEB];
    __shared__ unsigned short bns[TILEB];
    __shared__ int lcnt[1024];
    __shared__ int lbase[1024];
    int tot = E + N;
    int t0 = blockIdx.x * TILEB;
    int cnt = min(TILEB, tot - t0);
    for (int i = threadIdx.x; i < nbins; i += 256) lcnt[i] = 0;
    __syncthreads();
    for (int i = threadIdx.x; i < cnt; i += 256) {
        int e = t0 + i;
        int src, dst;
        if (e < E) { src = ei[e]; dst = ei[(size_t)E + e]; }
        else       { src = e - E; dst = src; }
        int b = dst >> 7;
        recs[i] = src | ((dst & 127) << 17);
        bns[i] = (unsigned short)b;
        atomicAdd(&lcnt[b], 1);
    }
    __syncthreads();
    for (int i = threadIdx.x; i < nbins; i += 256) {
        int c = lcnt[i];
        if (c) lbase[i] = atomicAdd(&binCur[i], c);
        lcnt[i] = 0;
    }
    __syncthreads();
    for (int i = threadIdx.x; i < cnt; i += 256) {
        int b = bns[i];
        int lp = atomicAdd(&lcnt[b], 1);
        binned[lbase[b] + lp] = recs[i];
    }
}

// fused: per-bin degree count -> in-bin prefix scan -> ptr write -> scatter
// (replaces k_bindeg + scanA/B/C + k_binscatter; ptr[n] = binOff[b] + excl_prefix)
__global__ __launch_bounds__(256) void k_binptr(const int* __restrict__ binOff,
    const int* __restrict__ binned, int* __restrict__ ptr,
    int* __restrict__ edge_src, int N, int nbins)
{
    __shared__ int cnt[NPBIN];
    __shared__ int cur[NPBIN];
    __shared__ int w0tot;
    int b = blockIdx.x, t = threadIdx.x;
    int s0 = binOff[b], s1 = binOff[b + 1];
    if (t < NPBIN) cnt[t] = 0;
    __syncthreads();
    for (int i = s0 + t; i < s1; i += 256)
        atomicAdd(&cnt[binned[i] >> 17], 1);
    __syncthreads();
    int v = 0, incl = 0;
    if (t < NPBIN) {
        int lane = t & 63;
        v = cnt[t];
        incl = v;
        #pragma unroll
        for (int off = 1; off < 64; off <<= 1) {
            int tt = __shfl_up(incl, off);
            if (lane >= off) incl += tt;
        }
        if (t == 63) w0tot = incl;
    }
    __syncthreads();
    if (t < NPBIN) {
        int base = s0 + ((t >= 64) ? w0tot : 0);
        int excl = base + incl - v;
        int node = b * NPBIN + t;
        if (node < N) ptr[node] = excl;
        cur[t] = excl;
    }
    if (b == nbins - 1 && t == 0) ptr[N] = s1;
    __syncthreads();
    for (int i = s0 + t; i < s1; i += 256) {
        int rec = binned[i];
        int p = atomicAdd(&cur[rec >> 17], 1);
        edge_src[p] = rec & 0x1FFFF;
    }
}

// ---------------- CSR build: fallback path ----------------
__global__ void k_count(const int* __restrict__ ei, int E, int N,
                        int* __restrict__ deg)
{
    int tot = E + N;
    for (int e = blockIdx.x * blockDim.x + threadIdx.x; e < tot;
         e += gridDim.x * blockDim.x) {
        int dst = (e < E) ? ei[(size_t)E + e] : (e - E);
        atomicAdd(&deg[dst], 1);
    }
}

__global__ void k_scatter(const int* __restrict__ ei, int E, int N,
                          int* __restrict__ cursor, int* __restrict__ edge_src)
{
    int tot = E + N;
    for (int e = blockIdx.x * blockDim.x + threadIdx.x; e < tot;
         e += gridDim.x * blockDim.x) {
        int src, dst;
        if (e < E) { src = ei[e]; dst = ei[(size_t)E + e]; }
        else       { src = e - E; dst = e - E; }
        int pos = atomicAdd(&cursor[dst], 1);
        edge_src[pos] = src;
    }
}

__global__ __launch_bounds__(256) void k_scanA(const int* __restrict__ deg,
    int* __restrict__ ptr, int* __restrict__ chunkSum)
{
    __shared__ int wtot[4];
    int b = blockIdx.x, t = threadIdx.x;
    int lane = t & 63, wave = t >> 6;
    int4 v = reinterpret_cast<const int4*>(deg + (size_t)b * CH)[t];
    int s = v.x + v.y + v.z + v.w;
    int incl = s;
    #pragma unroll
    for (int off = 1; off < 64; off <<= 1) {
        int tt = __shfl_up(incl, off);
        if (lane >= off) incl += tt;
    }
    if (lane == 63) wtot[wave] = incl;
    __syncthreads();
    int woff = 0;
    #pragma unroll
    for (int w = 0; w < 4; ++w) if (w < wave) woff += wtot[w];
    int excl = woff + incl - s;
    int i0 = b * CH + t * 4;
    ptr[i0 + 0] = excl;
    ptr[i0 + 1] = excl + v.x;
    ptr[i0 + 2] = excl + v.x + v.y;
    ptr[i0 + 3] = excl + v.x + v.y + v.z;
    if (t == 255) chunkSum[b] = woff + incl;
}

__global__ void k_scanB(const int* __restrict__ chunkSum, int* __restrict__ chunkOff,
                        int NB, int* __restrict__ ptrN)
{
    if (threadIdx.x == 0) {
        int c = 0;
        for (int b = 0; b < NB; ++b) { chunkOff[b] = c; c += chunkSum[b]; }
        *ptrN = c;
    }
}

__global__ __launch_bounds__(256) void k_scanC(int* __restrict__ ptr,
    int* __restrict__ cursor, const int* __restrict__ chunkOff, int N)
{
    int b = blockIdx.x;
    int off = chunkOff[b];
    int i0 = b * CH + threadIdx.x * 4;
    #pragma unroll
    for (int k = 0; k < 4; ++k) {
        int i = i0 + k;
        if (i < N) { int v = ptr[i] + off; ptr[i] = v; cursor[i] = v; }
    }
}

// -------- Layer-1 aggregation: two-phase softmax, 16-deep gather MLP --------
template<typename T>
__global__ __launch_bounds__(256) void k_agg1(const int* __restrict__ ptr,
    const int* __restrict__ edge_src, const T* __restrict__ h1,
    const float* __restrict__ asrc1, const float* __restrict__ adst1,
    const float* __restrict__ b1, const float* __restrict__ wsrc,
    const float* __restrict__ wdst, T* __restrict__ hmid,
    float* __restrict__ asrc2, float* __restrict__ adst2, int N)
{
    __shared__ float S1[4 * MAXD1 * H1];           // 16 KB per-wave stash
    int wave = threadIdx.x >> 6, lane = threadIdx.x & 63;
    float* st = S1 + wave * (MAXD1 * H1);
    int n = blockIdx.x * 4 + wave;
    if (n >= N) return;
    int start = ptr[n], end = ptr[n + 1];
    int deg = end - start;
    int h = lane >> 3;
    float o;

    if (deg <= MAXD1) {
        // ---- phase 1 ----
        int e_loc = lane >> 3, hh = lane & 7;
        float adsth = adst1[n * H1 + hh];
        float mloc = -1e30f;
        for (int eb = start, base = 0; eb < end; eb += 8, base += 64) {
            int e = eb + e_loc;
            float ev = -1e30f;
            if (e < end) {
                int s = edge_src[e];
                ev = asrc1[s * H1 + hh] + adsth;
                ev = ev > 0.f ? ev : NEG * ev;
                st[base + lane] = ev;
            }
            mloc = fmaxf(mloc, ev);
        }
        mloc = fmaxf(mloc, __shfl_xor(mloc, 8));
        mloc = fmaxf(mloc, __shfl_xor(mloc, 16));
        mloc = fmaxf(mloc, __shfl_xor(mloc, 32));
        __builtin_amdgcn_wave_barrier();
        float sloc = 0.f;
        for (int eb = start, base = 0; eb < end; eb += 8, base += 64) {
            if (eb + e_loc < end) {
                float p = __expf(st[base + lane] - mloc);
                st[base + lane] = p;
                sloc += p;
            }
        }
        sloc += __shfl_xor(sloc, 8);
        sloc += __shfl_xor(sloc, 16);
        sloc += __shfl_xor(sloc, 32);
        float inv = 1.f / (sloc + EPSS);
        __builtin_amdgcn_wave_barrier();
        float inv_c = __shfl(inv, h);               // head-layout -> channel-layout

        // ---- phase 2: 16-deep independent gathers ----
        float a0 = 0.f, a1 = 0.f, a2 = 0.f, a3 = 0.f;
        float a4 = 0.f, a5 = 0.f, a6 = 0.f, a7 = 0.f;
        int e = start;
        for (; e + 16 <= end; e += 16) {
            int r = e - start;
            int idx[16];
            #pragma unroll
            for (int j = 0; j < 16; ++j) idx[j] = edge_src[e + j];
            float hv[16];
            #pragma unroll
            for (int j = 0; j < 16; ++j)
                hv[j] = toF(h1[((size_t)(unsigned)idx[j] << 6) + lane]);
            float w[16];
            #pragma unroll
            for (int j = 0; j < 16; ++j) w[j] = st[(r + j) * H1 + h];
            a0 = fmaf(w[0],  hv[0],  a0); a1 = fmaf(w[1],  hv[1],  a1);
            a2 = fmaf(w[2],  hv[2],  a2); a3 = fmaf(w[3],  hv[3],  a3);
            a4 = fmaf(w[4],  hv[4],  a4); a5 = fmaf(w[5],  hv[5],  a5);
            a6 = fmaf(w[6],  hv[6],  a6); a7 = fmaf(w[7],  hv[7],  a7);
            a0 = fmaf(w[8],  hv[8],  a0); a1 = fmaf(w[9],  hv[9],  a1);
            a2 = fmaf(w[10], hv[10], a2); a3 = fmaf(w[11], hv[11], a3);
            a4 = fmaf(w[12], hv[12], a4); a5 = fmaf(w[13], hv[13], a5);
            a6 = fmaf(w[14], hv[14], a6); a7 = fmaf(w[15], hv[15], a7);
        }
        for (; e + 8 <= end; e += 8) {
            int r = e - start;
            int idx[8];
            #pragma unroll
            for (int j = 0; j < 8; ++j) idx[j] = edge_src[e + j];
            float hv[8];
            #pragma unroll
            for (int j = 0; j < 8; ++j)
                hv[j] = toF(h1[((size_t)(unsigned)idx[j] << 6) + lane]);
            a0 = fmaf(st[(r + 0) * H1 + h], hv[0], a0);
            a1 = fmaf(st[(r + 1) * H1 + h], hv[1], a1);
            a2 = fmaf(st[(r + 2) * H1 + h], hv[2], a2);
            a3 = fmaf(st[(r + 3) * H1 + h], hv[3], a3);
            a4 = fmaf(st[(r + 4) * H1 + h], hv[4], a4);
            a5 = fmaf(st[(r + 5) * H1 + h], hv[5], a5);
            a6 = fmaf(st[(r + 6) * H1 + h], hv[6], a6);
            a7 = fmaf(st[(r + 7) * H1 + h], hv[7], a7);
        }
        for (; e < end; ++e) {
            int s = edge_src[e];
            a0 = fmaf(st[(e - start) * H1 + h],
                      toF(h1[((size_t)(unsigned)s << 6) + lane]), a0);
        }
        float acc = ((a0 + a1) + (a2 + a3)) + ((a4 + a5) + (a6 + a7));
        o = acc * inv_c;
    } else {
        // ---- fallback: 8-chain online softmax ----
        float adst = adst1[n * H1 + h];
        float m[8], ss[8], aa[8];
        #pragma unroll
        for (int j = 0; j < 8; ++j) { m[j] = -1e30f; ss[j] = 0.f; aa[j] = 0.f; }
        int e = start;
        for (; e + 8 <= end; e += 8) {
            int idx[8];
            #pragma unroll
            for (int j = 0; j < 8; ++j) idx[j] = edge_src[e + j];
            #pragma unroll
            for (int j = 0; j < 8; ++j) {
                float t = asrc1[idx[j] * H1 + h] + adst;
                t = t > 0.f ? t : NEG * t;
                chain_upd(t, toF(h1[((size_t)(unsigned)idx[j] << 6) + lane]),
                          m[j], ss[j], aa[j]);
            }
        }
        for (; e < end; ++e) {
            int s = edge_src[e];
            float t = asrc1[s * H1 + h] + adst;
            t = t > 0.f ? t : NEG * t;
            chain_upd(t, toF(h1[((size_t)(unsigned)s << 6) + lane]), m[0], ss[0], aa[0]);
        }
        float M = fmaxf(fmaxf(fmaxf(m[0], m[1]), fmaxf(m[2], m[3])),
                        fmaxf(fmaxf(m[4], m[5]), fmaxf(m[6], m[7])));
        float sum = 0.f, acc = 0.f;
        #pragma unroll
        for (int j = 0; j < 8; ++j) {
            float sc = __expf(m[j] - M);
            sum = fmaf(ss[j], sc, sum);
            acc = fmaf(aa[j], sc, acc);
        }
        o = acc / (sum + EPSS);
    }

    o = o + b1[lane];
    o = o > 0.f ? o : (expf(o) - 1.f);   // ELU
    hmid[(size_t)n * C1 + lane] = fromF<T>(o);
    float vs = o * wsrc[lane];
    float vd = o * wdst[lane];
    #pragma unroll
    for (int off = 1; off < 64; off <<= 1) {
        vs += __shfl_xor(vs, off);
        vd += __shfl_xor(vd, off);
    }
    if (lane == 0) { asrc2[n] = vs; adst2[n] = vd; }
}

// ------ Layer-2 aggregation: two-phase softmax, 16-deep gather MLP; writes aggv ------
template<typename T>
__global__ __launch_bounds__(256) void k_agg2(const int* __restrict__ ptr,
    const int* __restrict__ edge_src, const T* __restrict__ hmid,
    const float* __restrict__ asrc2, const float* __restrict__ adst2,
    T* __restrict__ aggv_out, int N)
{
    __shared__ float S2[4 * MAXD2];                // 4 KB per-wave stash
    int wave = threadIdx.x >> 6, lane = threadIdx.x & 63;
    float* st = S2 + wave * MAXD2;
    int n = blockIdx.x * 4 + wave;
    if (n >= N) return;
    int start = ptr[n], end = ptr[n + 1];
    int deg = end - start;
    float adst = adst2[n];
    float aggv;

    if (deg <= MAXD2) {
        // ---- phase 1: lanes over edges ----
        float mloc = -1e30f;
        for (int e = start + lane; e < end; e += 64) {
            int s = edge_src[e];
            float ev = asrc2[s] + adst;
            ev = ev > 0.f ? ev : NEG * ev;
            st[e - start] = ev;
            mloc = fmaxf(mloc, ev);
        }
        #pragma unroll
        for (int off = 1; off < 64; off <<= 1)
            mloc = fmaxf(mloc, __shfl_xor(mloc, off));
        __builtin_amdgcn_wave_barrier();
        float sloc = 0.f;
        for (int e = start + lane; e < end; e += 64) {
            float p = __expf(st[e - start] - mloc);
            st[e - start] = p;
            sloc += p;
        }
        #pragma unroll
        for (int off = 1; off < 64; off <<= 1)
            sloc += __shfl_xor(sloc, off);
        float inv = 1.f / (sloc + EPSS);
        __builtin_amdgcn_wave_barrier();

        // ---- phase 2: 16-deep independent gathers ----
        float a0 = 0.f, a1 = 0.f, a2 = 0.f, a3 = 0.f;
        float a4 = 0.f, a5 = 0.f, a6 = 0.f, a7 = 0.f;
        int e = start;
        for (; e + 16 <= end; e += 16) {
            int r = e - start;
            int idx[16];
            #pragma unroll
            for (int j = 0; j < 16; ++j) idx[j] = edge_src[e + j];
            float hv[16];
            #pragma unroll
            for (int j = 0; j < 16; ++j)
                hv[j] = toF(hmid[((size_t)(unsigned)idx[j] << 6) + lane]);
            a0 = fmaf(st[r + 0],  hv[0],  a0); a1 = fmaf(st[r + 1],  hv[1],  a1);
            a2 = fmaf(st[r + 2],  hv[2],  a2); a3 = fmaf(st[r + 3],  hv[3],  a3);
            a4 = fmaf(st[r + 4],  hv[4],  a4); a5 = fmaf(st[r + 5],  hv[5],  a5);
            a6 = fmaf(st[r + 6],  hv[6],  a6); a7 = fmaf(st[r + 7],  hv[7],  a7);
            a0 = fmaf(st[r + 8],  hv[8],  a0); a1 = fmaf(st[r + 9],  hv[9],  a1);
            a2 = fmaf(st[r + 10], hv[10], a2); a3 = fmaf(st[r + 11], hv[11], a3);
            a4 = fmaf(st[r + 12], hv[12], a4); a5 = fmaf(st[r + 13], hv[13], a5);
            a6 = fmaf(st[r + 14], hv[14], a6); a7 = fmaf(st[r + 15], hv[15], a7);
        }
        for (; e + 8 <= end; e += 8) {
            int r = e - start;
            int idx[8];
            #pragma unroll
            for (int j = 0; j < 8; ++j) idx[j] = edge_src[e + j];
            float hv[8];
            #pragma unroll
            for (int j = 0; j < 8; ++j)
                hv[j] = toF(hmid[((size_t)(unsigned)idx[j] << 6) + lane]);
            a0 = fmaf(st[r + 0], hv[0], a0); a1 = fmaf(st[r + 1], hv[1], a1);
            a2 = fmaf(st[r + 2], hv[2], a2); a3 = fmaf(st[r + 3], hv[3], a3);
            a4 = fmaf(st[r + 4], hv[4], a4); a5 = fmaf(st[r + 5], hv[5], a5);
            a6 = fmaf(st[r + 6], hv[6], a6); a7 = fmaf(st[r + 7], hv[7], a7);
        }
        for (; e < end; ++e) {
            int s = edge_src[e];
            a0 = fmaf(st[e - start], toF(hmid[((size_t)(unsigned)s << 6) + lane]), a0);
        }
        float acc = ((a0 + a1) + (a2 + a3)) + ((a4 + a5) + (a6 + a7));
        aggv = acc * inv;
    } else {
        // ---- fallback: 8-chain online softmax ----
        float m[8], ss[8], aa[8];
        #pragma unroll
        for (int j = 0; j < 8; ++j) { m[j] = -1e30f; ss[j] = 0.f; aa[j] = 0.f; }
        int e = start;
        for (; e + 8 <= end; e += 8) {
            int idx[8];
            #pragma unroll
            for (int j = 0; j < 8; ++j) idx[j] = edge_src[e + j];
            #pragma unroll
            for (int j = 0; j < 8; ++j) {
                float t = asrc2[idx[j]] + adst;
                t = t > 0.f ? t : NEG * t;
                chain_upd(t, toF(hmid[((size_t)(unsigned)idx[j] << 6) + lane]),
                          m[j], ss[j], aa[j]);
            }
        }
        for (; e < end; ++e) {
            int s = edge_src[e];
            float t = asrc2[s] + adst;
            t = t > 0.f ? t : NEG * t;
            chain_upd(t, toF(hmid[((size_t)(unsigned)s << 6) + lane]), m[0], ss[0], aa[0]);
        }
        float M = fmaxf(fmaxf(fmaxf(m[0], m[1]), fmaxf(m[2], m[3])),
                        fmaxf(fmaxf(m[4], m[5]), fmaxf(m[6], m[7])));
        float sum = 0.f, acc = 0.f;
        #pragma unroll
        for (int j = 0; j < 8; ++j) {
            float sc = __expf(m[j] - M);
            sum = fmaf(ss[j], sc, sum);
            acc = fmaf(aa[j], sc, acc);
        }
        aggv = acc / (sum + EPSS);
    }
    aggv_out[(size_t)n * C1 + lane] = fromF<T>(aggv);
}

// ---------------- GEMM2: out = aggv @ W2 + b2 (dense, streaming) ----------------
template<typename T>
__global__ __launch_bounds__(256) void k_gemm2(const T* __restrict__ aggv,
    const float* __restrict__ W2, const float* __restrict__ b2,
    float* __restrict__ out, int N)
{
    __shared__ float Ws[C1 * D2];                  // 32 KB
    for (int i = threadIdx.x; i < C1 * D2 / 4; i += 256)
        reinterpret_cast<float4*>(Ws)[i] = reinterpret_cast<const float4*>(W2)[i];

    int wave = threadIdx.x >> 6, lane = threadIdx.x & 63;
    int n0 = blockIdx.x * NPB2 + wave * NPW2;

    float av[NPW2];
    #pragma unroll
    for (int j = 0; j < NPW2; ++j) {
        int n = n0 + j;
        av[j] = (n < N) ? toF(aggv[(size_t)n * C1 + lane]) : 0.f;
    }
    __syncthreads();

    float acc0[NPW2], acc1[NPW2];
    #pragma unroll
    for (int j = 0; j < NPW2; ++j) { acc0[j] = 0.f; acc1[j] = 0.f; }

    #pragma unroll 4
    for (int k = 0; k < 64; ++k) {
        float w0 = Ws[k * D2 + lane];
        float w1 = Ws[k * D2 + 64 + lane];
        #pragma unroll
        for (int j = 0; j < NPW2; ++j) {
            float xk = bcast_lane(av[j], k);
            acc0[j] = fmaf(xk, w0, acc0[j]);
            acc1[j] = fmaf(xk, w1, acc1[j]);
        }
    }

    float bb0 = b2[lane], bb1 = b2[64 + lane];
    #pragma unroll
    for (int j = 0; j < NPW2; ++j) {
        int n = n0 + j;
        if (n >= N) continue;
        out[(size_t)n * D2 + lane]      = acc0[j] + bb0;
        out[(size_t)n * D2 + 64 + lane] = acc1[j] + bb1;
    }
}

extern "C" void kernel_launch(void* const* d_in, const int* in_sizes, int n_in,
                              void* d_out, int out_size, void* d_ws, size_t ws_size,
                              hipStream_t stream)
{
    const float* x      = (const float*)d_in[0];
    const int*   ei     = (const int*)d_in[1];
    const float* W1     = (const float*)d_in[2];
    const float* a_src1 = (const float*)d_in[3];
    const float* a_dst1 = (const float*)d_in[4];
    const float* b1     = (const float*)d_in[5];
    const float* W2     = (const float*)d_in[6];
    const float* a_src2 = (const float*)d_in[7];
    const float* a_dst2 = (const float*)d_in[8];
    const float* b2     = (const float*)d_in[9];
    float* out = (float*)d_out;

    const int N = in_sizes[0] / FIN;
    const int E = in_sizes[1] / 2;
    const int Etot = E + N;
    const int NB = (N + CH - 1) / CH;     // scan chunks
    const size_t NP = (size_t)NB * CH;    // padded node count

    const size_t common =
        ((size_t)N * H1 * 4 + 255 & ~(size_t)255) * 2 +   // asrc1, adst1
        (((size_t)N * 4 + 255) & ~(size_t)255) * 2 +       // asrc2, adst2
        512 +                                              // wsrc, wdst
        (((size_t)NP * 4 + 255) & ~(size_t)255) * 2 +      // deg, cursor
        (((size_t)(NP + 1) * 4 + 255) & ~(size_t)255) +    // ptr
        (((size_t)NB * 4 + 255) & ~(size_t)255) * 2 +      // chunkSum, chunkOff
        (((size_t)Etot * 4 + 255) & ~(size_t)255) +        // edge_src
        4096;                                              // slack
    const bool f32path = ws_size >= common + 2 * ((size_t)N * C1 * 4 + 256);

    char* ws = (char*)d_ws;
    size_t off = 0;
    auto alloc = [&](size_t bytes) -> void* {
        void* p = ws + off;
        off = (off + bytes + 255) & ~(size_t)255;
        return p;
    };
    const size_t es = f32path ? 4 : 2;
    void*  h1v    = alloc((size_t)N * C1 * es);   // aliased: binned CSR records, later aggv
    void*  hmidv  = alloc((size_t)N * C1 * es);   // aliased: bin control arrays during CSR
    float* asrc1  = (float*)alloc((size_t)N * H1 * 4);
    float* adst1  = (float*)alloc((size_t)N * H1 * 4);
    float* asrc2  = (float*)alloc((size_t)N * 4);
    float* adst2  = (float*)alloc((size_t)N * 4);
    float* wsrc   = (float*)alloc(64 * 4);
    float* wdst   = (float*)alloc(64 * 4);
    int*   deg    = (int*)alloc(NP * 4);
    int*   ptr    = (int*)alloc((NP + 1) * 4);
    int*   cursor = (int*)alloc(NP * 4);
    int*   chunkSum = (int*)alloc((size_t)NB * 4);
    int*   chunkOff = (int*)alloc((size_t)NB * 4);
    int*   edge_src = (int*)alloc((size_t)Etot * 4);

    const int nodeBlocks = (N + 3) / 4;
    const int g1Blocks = (N + 63) / 64;
    const int g2Blocks = (N + NPB2 - 1) / NPB2;

    // ---- CSR build (dst-indexed) ----
    const int nbins = (N + NPBIN - 1) / NPBIN;
    const bool binpath = (N <= (1 << 17)) &&
                         ((size_t)Etot * 4 <= (size_t)N * C1 * es);
    if (binpath) {
        int* binned = (int*)h1v;                   // Etot ints
        int* binCnt = (int*)hmidv;                 // nbins
        int* binOff = binCnt + 1056;               // nbins+1
        int* binCur = binOff + 1056;               // nbins
        const int binBlocks = (Etot + TILEB - 1) / TILEB;
        hipMemsetAsync(binCnt, 0, (size_t)nbins * 4, stream);
        k_binhist<<<binBlocks, 256, 0, stream>>>(ei, E, N, nbins, binCnt);
        k_binscan<<<1, 256, 0, stream>>>(binCnt, binOff, binCur, nbins);
        k_bin<<<binBlocks, 256, 0, stream>>>(ei, E, N, nbins, binCur, binned);
        k_binptr<<<nbins, 256, 0, stream>>>(binOff, binned, ptr, edge_src, N, nbins);
    } else {
        hipMemsetAsync(deg, 0, NP * 4, stream);
        k_count<<<2048, 256, 0, stream>>>(ei, E, N, deg);
        k_scanA<<<NB, 256, 0, stream>>>(deg, ptr, chunkSum);
        k_scanB<<<1, 64, 0, stream>>>(chunkSum, chunkOff, NB, ptr + N);
        k_scanC<<<NB, 256, 0, stream>>>(ptr, cursor, chunkOff, N);
        k_scatter<<<2048, 256, 0, stream>>>(ei, E, N, cursor, edge_src);
    }

    k_wvec<<<1, 128, 0, stream>>>(W2, a_src2, a_dst2, wsrc, wdst);

    if (f32path) {
        float* h1 = (float*)h1v; float* hmid = (float*)hmidv;
        k_gemm1<float><<<g1Blocks, 256, 0, stream>>>(x, W1, a_src1, a_dst1, h1, asrc1, adst1, N);
        k_agg1<float><<<nodeBlocks, 256, 0, stream>>>(ptr, edge_src, h1, asrc1, adst1, b1,
                                                      wsrc, wdst, hmid, asrc2, adst2, N);
        float* aggv = (float*)h1v;   // h1 dead after agg1
        k_agg2<float><<<nodeBlocks, 256, 0, stream>>>(ptr, edge_src, hmid, asrc2, adst2, aggv, N);
        k_gemm2<float><<<g2Blocks, 256, 0, stream>>>(aggv, W2, b2, out, N);
    } else {
        __hip_bfloat16* h1 = (__hip_bfloat16*)h1v; __hip_bfloat16* hmid = (__hip_bfloat16*)hmidv;
        k_gemm1<__hip_bfloat16><<<g1Blocks, 256, 0, stream>>>(x, W1, a_src1, a_dst1, h1, asrc1, adst1, N);
        k_agg1<__hip_bfloat16><<<nodeBlocks, 256, 0, stream>>>(ptr, edge_src, h1, asrc1, adst1, b1,
                                                               wsrc, wdst, hmid, asrc2, adst2, N);
        __hip_bfloat16* aggv = (__hip_bfloat16*)h1v;   // h1 dead after agg1
        k_agg2<__hip_bfloat16><<<nodeBlocks, 256, 0, stream>>>(ptr, edge_src, hmid, asrc2, adst2, aggv, N);
        k_gemm2<__hip_bfloat16><<<g2Blocks, 256, 0, stream>>>(aggv, W2, b2, out, N);
    }
}

// Round 9
// 344.550 us; speedup vs baseline: 1.0774x; 1.0416x over previous
//
#include <hip/hip_runtime.h>
#include <hip/hip_bf16.h>
#include <cstdint>

#define H1 8
#define C1 64      // H1*D1
#define D2 128
#define FIN 256
#define NEG 0.2f
#define EPSS 1e-16f
#define CH 1024    // nodes per scan chunk
#define NPW2 8     // gemm2: nodes per wave
#define NPB2 32    // gemm2: nodes per block
#define XPAD 264   // Wb global row stride in bf16 (c-major)
#define XH 136     // gemm1 LDS half-K row stride in bf16 (272B = 17*16B)
#define HP 68      // gemm1 epilogue f32 row stride
#define NPBIN 128  // nodes per bin (CSR binning)
#define TILEB 4096 // edges per k_bin block
#define MAXD1 128  // agg1 fast-path degree cap
#define MAXD2 256  // agg2 fast-path degree cap

template<typename T> __device__ __forceinline__ float toF(T v);
template<> __device__ __forceinline__ float toF<float>(float v) { return v; }
template<> __device__ __forceinline__ float toF<__hip_bfloat16>(__hip_bfloat16 v) { return __bfloat162float(v); }
template<typename T> __device__ __forceinline__ T fromF(float v);
template<> __device__ __forceinline__ float fromF<float>(float v) { return v; }
template<> __device__ __forceinline__ __hip_bfloat16 fromF<__hip_bfloat16>(float v) { return __float2bfloat16(v); }

__device__ __forceinline__ float bcast_lane(float v, int lane) {
    return __int_as_float(__builtin_amdgcn_readlane(__float_as_int(v), lane));
}

__device__ __forceinline__ unsigned pk_bf16(float lo, float hi) {
    unsigned a = (unsigned)__bfloat16_as_ushort(__float2bfloat16(lo));
    unsigned b = (unsigned)__bfloat16_as_ushort(__float2bfloat16(hi));
    return a | (b << 16);
}

typedef __attribute__((ext_vector_type(8))) short bf16x8;
typedef __attribute__((ext_vector_type(4))) float f32x4;

// online-softmax chain update (fallback path)
__device__ __forceinline__ void chain_upd(float ev, float hv,
                                          float& m, float& s, float& a)
{
    float mn = fmaxf(m, ev);
    float sc = __expf(m - mn);
    float p  = __expf(ev - mn);
    s = fmaf(s, sc, p);
    a = fmaf(a, sc, p * hv);
    m = mn;
}

// ---------------- W1 -> bf16 padded [c][k] layout (once) ----------------
__global__ __launch_bounds__(256) void k_wcvt(const float* __restrict__ W1,
    unsigned short* __restrict__ Wb)
{
    int t = blockIdx.x * 256 + threadIdx.x;       // 8192 threads: c=t>>7, kp=t&127
    int c = t >> 7, kp = t & 127;
    if (c < C1) {
        float f0 = W1[(2 * kp) * C1 + c];
        float f1 = W1[(2 * kp + 1) * C1 + c];
        *reinterpret_cast<unsigned*>(&Wb[c * XPAD + 2 * kp]) = pk_bf16(f0, f1);
    }
}

// ---------------- GEMM1 v3 (MFMA, K-split): h1 = x @ W1, fused alphas ----------------
// LDS = 34.8 KB -> 4 blocks/CU (16 waves) for x-stream latency hiding.
template<typename T>
__global__ __launch_bounds__(256) void k_gemm1(const float* __restrict__ x,
    const unsigned short* __restrict__ Wb, const float* __restrict__ a_src1,
    const float* __restrict__ a_dst1, T* __restrict__ h1,
    float* __restrict__ asrc1, float* __restrict__ adst1, int N)
{
    __shared__ alignas(16) unsigned short Xs[64 * XH];   // 17408 B (reused as f32 Hs)
    __shared__ alignas(16) unsigned short Wt[64 * XH];   // 17408 B: Wt[c][k-half]
    int tid = threadIdx.x;
    int wave = tid >> 6, lane = tid & 63;
    int nodeBase = blockIdx.x * 64;
    int m = lane & 15, kg = lane >> 4;
    int arow = wave * 16 + m;

    f32x4 acc[4];
    #pragma unroll
    for (int t = 0; t < 4; ++t) acc[t] = (f32x4){0.f, 0.f, 0.f, 0.f};

    #pragma unroll
    for (int kh = 0; kh < 2; ++kh) {
        // stage W half (bf16 copy, 16 KB from L2): 1024 x 16B chunks
        for (int i = tid; i < 1024; i += 256) {
            int c = i >> 4, ch = i & 15;
            *reinterpret_cast<uint4*>(&Wt[c * XH + ch * 8]) =
                *reinterpret_cast<const uint4*>(&Wb[c * XPAD + kh * 128 + ch * 8]);
        }
        // stage x half: 2048 float4 loads, pack bf16
        for (int i = tid; i < 2048; i += 256) {
            int r = i >> 5, q = i & 31;
            int n = nodeBase + r;
            float4 v = (n < N) ? reinterpret_cast<const float4*>(x)[(size_t)n * 64 + kh * 32 + q]
                               : make_float4(0.f, 0.f, 0.f, 0.f);
            *reinterpret_cast<uint2*>(&Xs[r * XH + q * 4]) =
                make_uint2(pk_bf16(v.x, v.y), pk_bf16(v.z, v.w));
        }
        __syncthreads();
        #pragma unroll
        for (int ks = 0; ks < 4; ++ks) {
            int k0 = ks * 32 + kg * 8;
            bf16x8 a = *reinterpret_cast<const bf16x8*>(&Xs[arow * XH + k0]);
            #pragma unroll
            for (int t = 0; t < 4; ++t) {
                bf16x8 b = *reinterpret_cast<const bf16x8*>(&Wt[(t * 16 + m) * XH + k0]);
                acc[t] = __builtin_amdgcn_mfma_f32_16x16x32_bf16(a, b, acc[t], 0, 0, 0);
            }
        }
        __syncthreads();
    }

    // epilogue: spill acc to LDS (Hs aliases Xs: 64*68*4 = 17408 B exact fit)
    float* Hs = reinterpret_cast<float*>(Xs);
    int crow = (lane >> 4) * 4;
    #pragma unroll
    for (int t = 0; t < 4; ++t)
        #pragma unroll
        for (int r = 0; r < 4; ++r)
            Hs[(wave * 16 + crow + r) * HP + t * 16 + m] = acc[t][r];
    __syncthreads();

    float as_l = a_src1[lane], ad_l = a_dst1[lane];
    int n0 = nodeBase + wave * 16;
    #pragma unroll
    for (int i = 0; i < 16; ++i) {
        int n = n0 + i;
        if (n >= N) break;
        float hv = Hs[(wave * 16 + i) * HP + lane];
        h1[(size_t)n * C1 + lane] = fromF<T>(hv);
        float vs = hv * as_l, vd = hv * ad_l;
        #pragma unroll
        for (int off = 1; off < 8; off <<= 1) {
            vs += __shfl_xor(vs, off);
            vd += __shfl_xor(vd, off);
        }
        if ((lane & 7) == 0) {
            asrc1[n * H1 + (lane >> 3)] = vs;
            adst1[n * H1 + (lane >> 3)] = vd;
        }
    }
}

// ---------------- wsrc/wdst = W2 @ a_src2 / W2 @ a_dst2  (64 each) ----------------
__global__ __launch_bounds__(128) void k_wvec(const float* __restrict__ W2,
    const float* __restrict__ a_src2, const float* __restrict__ a_dst2,
    float* __restrict__ wsrc, float* __restrict__ wdst)
{
    int t = threadIdx.x;
    int k = t & 63;
    const float* a = (t < 64) ? a_src2 : a_dst2;
    float s = 0.f;
    for (int c = 0; c < D2; ++c) s = fmaf(W2[k * D2 + c], a[c], s);
    if (t < 64) wsrc[k] = s; else wdst[k] = s;
}

// ---------------- CSR build: binned path (N <= 2^17) ----------------
__global__ __launch_bounds__(256) void k_binhist(const int* __restrict__ ei, int E, int N,
    int nbins, int* __restrict__ binCnt)
{
    __shared__ int lcnt[1024];
    int tot = E + N;
    int t0 = blockIdx.x * TILEB;
    int cnt = min(TILEB, tot - t0);
    for (int i = threadIdx.x; i < nbins; i += 256) lcnt[i] = 0;
    __syncthreads();
    for (int i = threadIdx.x; i < cnt; i += 256) {
        int e = t0 + i;
        int dst = (e < E) ? ei[(size_t)E + e] : (e - E);
        atomicAdd(&lcnt[dst >> 7], 1);
    }
    __syncthreads();
    for (int i = threadIdx.x; i < nbins; i += 256)
        if (lcnt[i]) atomicAdd(&binCnt[i], lcnt[i]);
}

__global__ __launch_bounds__(256) void k_binscan(const int* __restrict__ binCnt,
    int* __restrict__ binOff, int* __restrict__ binCur, int nbins)
{
    __shared__ int wtot[4];
    int t = threadIdx.x, lane = t & 63, wave = t >> 6;
    int v[4];
    #pragma unroll
    for (int j = 0; j < 4; ++j) {
        int idx = t * 4 + j;
        v[j] = (idx < nbins) ? binCnt[idx] : 0;
    }
    int s = v[0] + v[1] + v[2] + v[3];
    int incl = s;
    #pragma unroll
    for (int off = 1; off < 64; off <<= 1) {
        int tt = __shfl_up(incl, off);
        if (lane >= off) incl += tt;
    }
    if (lane == 63) wtot[wave] = incl;
    __syncthreads();
    int woff = 0;
    #pragma unroll
    for (int w = 0; w < 4; ++w) if (w < wave) woff += wtot[w];
    int run = woff + incl - s;
    #pragma unroll
    for (int j = 0; j < 4; ++j) {
        int idx = t * 4 + j;
        if (idx < nbins) { binOff[idx] = run; binCur[idx] = run; }
        run += v[j];
    }
    if (t == 255) binOff[nbins] = woff + incl;
}

__global__ __launch_bounds__(256) void k_bin(const int* __restrict__ ei, int E, int N,
    int nbins, int* __restrict__ binCur, int* __restrict__ binned)
{
    __shared__ int recs[TILEB];
    __shared__ unsigned short bns[TILEB];
    __shared__ int lcnt[1024];
    __shared__ int lbase[1024];
    int tot = E + N;
    int t0 = blockIdx.x * TILEB;
    int cnt = min(TILEB, tot - t0);
    for (int i = threadIdx.x; i < nbins; i += 256) lcnt[i] = 0;
    __syncthreads();
    for (int i = threadIdx.x; i < cnt; i += 256) {
        int e = t0 + i;
        int src, dst;
        if (e < E) { src = ei[e]; dst = ei[(size_t)E + e]; }
        else       { src = e - E; dst = src; }
        int b = dst >> 7;
        recs[i] = src | ((dst & 127) << 17);
        bns[i] = (unsigned short)b;
        atomicAdd(&lcnt[b], 1);
    }
    __syncthreads();
    for (int i = threadIdx.x; i < nbins; i += 256) {
        int c = lcnt[i];
        if (c) lbase[i] = atomicAdd(&binCur[i], c);
        lcnt[i] = 0;
    }
    __syncthreads();
    for (int i = threadIdx.x; i < cnt; i += 256) {
        int b = bns[i];
        int lp = atomicAdd(&lcnt[b], 1);
        binned[lbase[b] + lp] = recs[i];
    }
}

// fused: per-bin degree count -> in-bin prefix scan -> ptr write -> scatter
__global__ __launch_bounds__(256) void k_binptr(const int* __restrict__ binOff,
    const int* __restrict__ binned, int* __restrict__ ptr,
    int* __restrict__ edge_src, int N, int nbins)
{
    __shared__ int cnt[NPBIN];
    __shared__ int cur[NPBIN];
    __shared__ int w0tot;
    int b = blockIdx.x, t = threadIdx.x;
    int s0 = binOff[b], s1 = binOff[b + 1];
    if (t < NPBIN) cnt[t] = 0;
    __syncthreads();
    for (int i = s0 + t; i < s1; i += 256)
        atomicAdd(&cnt[binned[i] >> 17], 1);
    __syncthreads();
    int v = 0, incl = 0;
    if (t < NPBIN) {
        int lane = t & 63;
        v = cnt[t];
        incl = v;
        #pragma unroll
        for (int off = 1; off < 64; off <<= 1) {
            int tt = __shfl_up(incl, off);
            if (lane >= off) incl += tt;
        }
        if (t == 63) w0tot = incl;
    }
    __syncthreads();
    if (t < NPBIN) {
        int base = s0 + ((t >= 64) ? w0tot : 0);
        int excl = base + incl - v;
        int node = b * NPBIN + t;
        if (node < N) ptr[node] = excl;
        cur[t] = excl;
    }
    if (b == nbins - 1 && t == 0) ptr[N] = s1;
    __syncthreads();
    for (int i = s0 + t; i < s1; i += 256) {
        int rec = binned[i];
        int p = atomicAdd(&cur[rec >> 17], 1);
        edge_src[p] = rec & 0x1FFFF;
    }
}

// ---------------- CSR build: fallback path ----------------
__global__ void k_count(const int* __restrict__ ei, int E, int N,
                        int* __restrict__ deg)
{
    int tot = E + N;
    for (int e = blockIdx.x * blockDim.x + threadIdx.x; e < tot;
         e += gridDim.x * blockDim.x) {
        int dst = (e < E) ? ei[(size_t)E + e] : (e - E);
        atomicAdd(&deg[dst], 1);
    }
}

__global__ void k_scatter(const int* __restrict__ ei, int E, int N,
                          int* __restrict__ cursor, int* __restrict__ edge_src)
{
    int tot = E + N;
    for (int e = blockIdx.x * blockDim.x + threadIdx.x; e < tot;
         e += gridDim.x * blockDim.x) {
        int src, dst;
        if (e < E) { src = ei[e]; dst = ei[(size_t)E + e]; }
        else       { src = e - E; dst = e - E; }
        int pos = atomicAdd(&cursor[dst], 1);
        edge_src[pos] = src;
    }
}

__global__ __launch_bounds__(256) void k_scanA(const int* __restrict__ deg,
    int* __restrict__ ptr, int* __restrict__ chunkSum)
{
    __shared__ int wtot[4];
    int b = blockIdx.x, t = threadIdx.x;
    int lane = t & 63, wave = t >> 6;
    int4 v = reinterpret_cast<const int4*>(deg + (size_t)b * CH)[t];
    int s = v.x + v.y + v.z + v.w;
    int incl = s;
    #pragma unroll
    for (int off = 1; off < 64; off <<= 1) {
        int tt = __shfl_up(incl, off);
        if (lane >= off) incl += tt;
    }
    if (lane == 63) wtot[wave] = incl;
    __syncthreads();
    int woff = 0;
    #pragma unroll
    for (int w = 0; w < 4; ++w) if (w < wave) woff += wtot[w];
    int excl = woff + incl - s;
    int i0 = b * CH + t * 4;
    ptr[i0 + 0] = excl;
    ptr[i0 + 1] = excl + v.x;
    ptr[i0 + 2] = excl + v.x + v.y;
    ptr[i0 + 3] = excl + v.x + v.y + v.z;
    if (t == 255) chunkSum[b] = woff + incl;
}

__global__ void k_scanB(const int* __restrict__ chunkSum, int* __restrict__ chunkOff,
                        int NB, int* __restrict__ ptrN)
{
    if (threadIdx.x == 0) {
        int c = 0;
        for (int b = 0; b < NB; ++b) { chunkOff[b] = c; c += chunkSum[b]; }
        *ptrN = c;
    }
}

__global__ __launch_bounds__(256) void k_scanC(int* __restrict__ ptr,
    int* __restrict__ cursor, const int* __restrict__ chunkOff, int N)
{
    int b = blockIdx.x;
    int off = chunkOff[b];
    int i0 = b * CH + threadIdx.x * 4;
    #pragma unroll
    for (int k = 0; k < 4; ++k) {
        int i = i0 + k;
        if (i < N) { int v = ptr[i] + off; ptr[i] = v; cursor[i] = v; }
    }
}

// -------- Layer-1 aggregation: two-phase softmax, 8-deep gather MLP --------
template<typename T>
__global__ __launch_bounds__(256) void k_agg1(const int* __restrict__ ptr,
    const int* __restrict__ edge_src, const T* __restrict__ h1,
    const float* __restrict__ asrc1, const float* __restrict__ adst1,
    const float* __restrict__ b1, const float* __restrict__ wsrc,
    const float* __restrict__ wdst, T* __restrict__ hmid,
    float* __restrict__ asrc2, float* __restrict__ adst2, int N)
{
    __shared__ float S1[4 * MAXD1 * H1];           // 16 KB per-wave stash
    int wave = threadIdx.x >> 6, lane = threadIdx.x & 63;
    float* st = S1 + wave * (MAXD1 * H1);
    int n = blockIdx.x * 4 + wave;
    if (n >= N) return;
    int start = ptr[n], end = ptr[n + 1];
    int deg = end - start;
    int h = lane >> 3;
    float o;

    if (deg <= MAXD1) {
        // ---- phase 1 ----
        int e_loc = lane >> 3, hh = lane & 7;
        float adsth = adst1[n * H1 + hh];
        float mloc = -1e30f;
        for (int eb = start, base = 0; eb < end; eb += 8, base += 64) {
            int e = eb + e_loc;
            float ev = -1e30f;
            if (e < end) {
                int s = edge_src[e];
                ev = asrc1[s * H1 + hh] + adsth;
                ev = ev > 0.f ? ev : NEG * ev;
                st[base + lane] = ev;
            }
            mloc = fmaxf(mloc, ev);
        }
        mloc = fmaxf(mloc, __shfl_xor(mloc, 8));
        mloc = fmaxf(mloc, __shfl_xor(mloc, 16));
        mloc = fmaxf(mloc, __shfl_xor(mloc, 32));
        __builtin_amdgcn_wave_barrier();
        float sloc = 0.f;
        for (int eb = start, base = 0; eb < end; eb += 8, base += 64) {
            if (eb + e_loc < end) {
                float p = __expf(st[base + lane] - mloc);
                st[base + lane] = p;
                sloc += p;
            }
        }
        sloc += __shfl_xor(sloc, 8);
        sloc += __shfl_xor(sloc, 16);
        sloc += __shfl_xor(sloc, 32);
        float inv = 1.f / (sloc + EPSS);
        __builtin_amdgcn_wave_barrier();
        float inv_c = __shfl(inv, h);               // head-layout -> channel-layout

        // ---- phase 2: 8-deep independent gathers ----
        float a0 = 0.f, a1 = 0.f, a2 = 0.f, a3 = 0.f;
        float a4 = 0.f, a5 = 0.f, a6 = 0.f, a7 = 0.f;
        int e = start;
        for (; e + 8 <= end; e += 8) {
            int r = e - start;
            int i0 = edge_src[e + 0]; int i1 = edge_src[e + 1];
            int i2 = edge_src[e + 2]; int i3 = edge_src[e + 3];
            int i4 = edge_src[e + 4]; int i5 = edge_src[e + 5];
            int i6 = edge_src[e + 6]; int i7 = edge_src[e + 7];
            float w0 = st[(r + 0) * H1 + h]; float w1 = st[(r + 1) * H1 + h];
            float w2 = st[(r + 2) * H1 + h]; float w3 = st[(r + 3) * H1 + h];
            float w4 = st[(r + 4) * H1 + h]; float w5 = st[(r + 5) * H1 + h];
            float w6 = st[(r + 6) * H1 + h]; float w7 = st[(r + 7) * H1 + h];
            a0 = fmaf(w0, toF(h1[((size_t)(unsigned)i0 << 6) + lane]), a0);
            a1 = fmaf(w1, toF(h1[((size_t)(unsigned)i1 << 6) + lane]), a1);
            a2 = fmaf(w2, toF(h1[((size_t)(unsigned)i2 << 6) + lane]), a2);
            a3 = fmaf(w3, toF(h1[((size_t)(unsigned)i3 << 6) + lane]), a3);
            a4 = fmaf(w4, toF(h1[((size_t)(unsigned)i4 << 6) + lane]), a4);
            a5 = fmaf(w5, toF(h1[((size_t)(unsigned)i5 << 6) + lane]), a5);
            a6 = fmaf(w6, toF(h1[((size_t)(unsigned)i6 << 6) + lane]), a6);
            a7 = fmaf(w7, toF(h1[((size_t)(unsigned)i7 << 6) + lane]), a7);
        }
        for (; e < end; ++e) {
            int s = edge_src[e];
            a0 = fmaf(st[(e - start) * H1 + h],
                      toF(h1[((size_t)(unsigned)s << 6) + lane]), a0);
        }
        float acc = ((a0 + a1) + (a2 + a3)) + ((a4 + a5) + (a6 + a7));
        o = acc * inv_c;
    } else {
        // ---- fallback: 8-chain online softmax ----
        float adst = adst1[n * H1 + h];
        float m[8], ss[8], aa[8];
        #pragma unroll
        for (int j = 0; j < 8; ++j) { m[j] = -1e30f; ss[j] = 0.f; aa[j] = 0.f; }
        int e = start;
        for (; e + 8 <= end; e += 8) {
            int idx[8];
            #pragma unroll
            for (int j = 0; j < 8; ++j) idx[j] = edge_src[e + j];
            #pragma unroll
            for (int j = 0; j < 8; ++j) {
                float t = asrc1[idx[j] * H1 + h] + adst;
                t = t > 0.f ? t : NEG * t;
                chain_upd(t, toF(h1[((size_t)(unsigned)idx[j] << 6) + lane]),
                          m[j], ss[j], aa[j]);
            }
        }
        for (; e < end; ++e) {
            int s = edge_src[e];
            float t = asrc1[s * H1 + h] + adst;
            t = t > 0.f ? t : NEG * t;
            chain_upd(t, toF(h1[((size_t)(unsigned)s << 6) + lane]), m[0], ss[0], aa[0]);
        }
        float M = fmaxf(fmaxf(fmaxf(m[0], m[1]), fmaxf(m[2], m[3])),
                        fmaxf(fmaxf(m[4], m[5]), fmaxf(m[6], m[7])));
        float sum = 0.f, acc = 0.f;
        #pragma unroll
        for (int j = 0; j < 8; ++j) {
            float sc = __expf(m[j] - M);
            sum = fmaf(ss[j], sc, sum);
            acc = fmaf(aa[j], sc, acc);
        }
        o = acc / (sum + EPSS);
    }

    o = o + b1[lane];
    o = o > 0.f ? o : (expf(o) - 1.f);   // ELU
    hmid[(size_t)n * C1 + lane] = fromF<T>(o);
    float vs = o * wsrc[lane];
    float vd = o * wdst[lane];
    #pragma unroll
    for (int off = 1; off < 64; off <<= 1) {
        vs += __shfl_xor(vs, off);
        vd += __shfl_xor(vd, off);
    }
    if (lane == 0) { asrc2[n] = vs; adst2[n] = vd; }
}

// ------ Layer-2 aggregation: two-phase softmax, 8-deep gather MLP; writes aggv ------
template<typename T>
__global__ __launch_bounds__(256) void k_agg2(const int* __restrict__ ptr,
    const int* __restrict__ edge_src, const T* __restrict__ hmid,
    const float* __restrict__ asrc2, const float* __restrict__ adst2,
    T* __restrict__ aggv_out, int N)
{
    __shared__ float S2[4 * MAXD2];                // 4 KB per-wave stash
    int wave = threadIdx.x >> 6, lane = threadIdx.x & 63;
    float* st = S2 + wave * MAXD2;
    int n = blockIdx.x * 4 + wave;
    if (n >= N) return;
    int start = ptr[n], end = ptr[n + 1];
    int deg = end - start;
    float adst = adst2[n];
    float aggv;

    if (deg <= MAXD2) {
        // ---- phase 1: lanes over edges ----
        float mloc = -1e30f;
        for (int e = start + lane; e < end; e += 64) {
            int s = edge_src[e];
            float ev = asrc2[s] + adst;
            ev = ev > 0.f ? ev : NEG * ev;
            st[e - start] = ev;
            mloc = fmaxf(mloc, ev);
        }
        #pragma unroll
        for (int off = 1; off < 64; off <<= 1)
            mloc = fmaxf(mloc, __shfl_xor(mloc, off));
        __builtin_amdgcn_wave_barrier();
        float sloc = 0.f;
        for (int e = start + lane; e < end; e += 64) {
            float p = __expf(st[e - start] - mloc);
            st[e - start] = p;
            sloc += p;
        }
        #pragma unroll
        for (int off = 1; off < 64; off <<= 1)
            sloc += __shfl_xor(sloc, off);
        float inv = 1.f / (sloc + EPSS);
        __builtin_amdgcn_wave_barrier();

        // ---- phase 2: 8-deep independent gathers ----
        float a0 = 0.f, a1 = 0.f, a2 = 0.f, a3 = 0.f;
        float a4 = 0.f, a5 = 0.f, a6 = 0.f, a7 = 0.f;
        int e = start;
        for (; e + 8 <= end; e += 8) {
            int r = e - start;
            int i0 = edge_src[e + 0]; int i1 = edge_src[e + 1];
            int i2 = edge_src[e + 2]; int i3 = edge_src[e + 3];
            int i4 = edge_src[e + 4]; int i5 = edge_src[e + 5];
            int i6 = edge_src[e + 6]; int i7 = edge_src[e + 7];
            a0 = fmaf(st[r + 0], toF(hmid[((size_t)(unsigned)i0 << 6) + lane]), a0);
            a1 = fmaf(st[r + 1], toF(hmid[((size_t)(unsigned)i1 << 6) + lane]), a1);
            a2 = fmaf(st[r + 2], toF(hmid[((size_t)(unsigned)i2 << 6) + lane]), a2);
            a3 = fmaf(st[r + 3], toF(hmid[((size_t)(unsigned)i3 << 6) + lane]), a3);
            a4 = fmaf(st[r + 4], toF(hmid[((size_t)(unsigned)i4 << 6) + lane]), a4);
            a5 = fmaf(st[r + 5], toF(hmid[((size_t)(unsigned)i5 << 6) + lane]), a5);
            a6 = fmaf(st[r + 6], toF(hmid[((size_t)(unsigned)i6 << 6) + lane]), a6);
            a7 = fmaf(st[r + 7], toF(hmid[((size_t)(unsigned)i7 << 6) + lane]), a7);
        }
        for (; e < end; ++e) {
            int s = edge_src[e];
            a0 = fmaf(st[e - start], toF(hmid[((size_t)(unsigned)s << 6) + lane]), a0);
        }
        float acc = ((a0 + a1) + (a2 + a3)) + ((a4 + a5) + (a6 + a7));
        aggv = acc * inv;
    } else {
        // ---- fallback: 8-chain online softmax ----
        float m[8], ss[8], aa[8];
        #pragma unroll
        for (int j = 0; j < 8; ++j) { m[j] = -1e30f; ss[j] = 0.f; aa[j] = 0.f; }
        int e = start;
        for (; e + 8 <= end; e += 8) {
            int idx[8];
            #pragma unroll
            for (int j = 0; j < 8; ++j) idx[j] = edge_src[e + j];
            #pragma unroll
            for (int j = 0; j < 8; ++j) {
                float t = asrc2[idx[j]] + adst;
                t = t > 0.f ? t : NEG * t;
                chain_upd(t, toF(hmid[((size_t)(unsigned)idx[j] << 6) + lane]),
                          m[j], ss[j], aa[j]);
            }
        }
        for (; e < end; ++e) {
            int s = edge_src[e];
            float t = asrc2[s] + adst;
            t = t > 0.f ? t : NEG * t;
            chain_upd(t, toF(hmid[((size_t)(unsigned)s << 6) + lane]), m[0], ss[0], aa[0]);
        }
        float M = fmaxf(fmaxf(fmaxf(m[0], m[1]), fmaxf(m[2], m[3])),
                        fmaxf(fmaxf(m[4], m[5]), fmaxf(m[6], m[7])));
        float sum = 0.f, acc = 0.f;
        #pragma unroll
        for (int j = 0; j < 8; ++j) {
            float sc = __expf(m[j] - M);
            sum = fmaf(ss[j], sc, sum);
            acc = fmaf(aa[j], sc, acc);
        }
        aggv = acc / (sum + EPSS);
    }
    aggv_out[(size_t)n * C1 + lane] = fromF<T>(aggv);
}

// ---------------- GEMM2: out = aggv @ W2 + b2 (dense, streaming) ----------------
template<typename T>
__global__ __launch_bounds__(256) void k_gemm2(const T* __restrict__ aggv,
    const float* __restrict__ W2, const float* __restrict__ b2,
    float* __restrict__ out, int N)
{
    __shared__ float Ws[C1 * D2];                  // 32 KB
    for (int i = threadIdx.x; i < C1 * D2 / 4; i += 256)
        reinterpret_cast<float4*>(Ws)[i] = reinterpret_cast<const float4*>(W2)[i];

    int wave = threadIdx.x >> 6, lane = threadIdx.x & 63;
    int n0 = blockIdx.x * NPB2 + wave * NPW2;

    float av[NPW2];
    #pragma unroll
    for (int j = 0; j < NPW2; ++j) {
        int n = n0 + j;
        av[j] = (n < N) ? toF(aggv[(size_t)n * C1 + lane]) : 0.f;
    }
    __syncthreads();

    float acc0[NPW2], acc1[NPW2];
    #pragma unroll
    for (int j = 0; j < NPW2; ++j) { acc0[j] = 0.f; acc1[j] = 0.f; }

    #pragma unroll 4
    for (int k = 0; k < 64; ++k) {
        float w0 = Ws[k * D2 + lane];
        float w1 = Ws[k * D2 + 64 + lane];
        #pragma unroll
        for (int j = 0; j < NPW2; ++j) {
            float xk = bcast_lane(av[j], k);
            acc0[j] = fmaf(xk, w0, acc0[j]);
            acc1[j] = fmaf(xk, w1, acc1[j]);
        }
    }

    float bb0 = b2[lane], bb1 = b2[64 + lane];
    #pragma unroll
    for (int j = 0; j < NPW2; ++j) {
        int n = n0 + j;
        if (n >= N) continue;
        out[(size_t)n * D2 + lane]      = acc0[j] + bb0;
        out[(size_t)n * D2 + 64 + lane] = acc1[j] + bb1;
    }
}

extern "C" void kernel_launch(void* const* d_in, const int* in_sizes, int n_in,
                              void* d_out, int out_size, void* d_ws, size_t ws_size,
                              hipStream_t stream)
{
    const float* x      = (const float*)d_in[0];
    const int*   ei     = (const int*)d_in[1];
    const float* W1     = (const float*)d_in[2];
    const float* a_src1 = (const float*)d_in[3];
    const float* a_dst1 = (const float*)d_in[4];
    const float* b1     = (const float*)d_in[5];
    const float* W2     = (const float*)d_in[6];
    const float* a_src2 = (const float*)d_in[7];
    const float* a_dst2 = (const float*)d_in[8];
    const float* b2     = (const float*)d_in[9];
    float* out = (float*)d_out;

    const int N = in_sizes[0] / FIN;
    const int E = in_sizes[1] / 2;
    const int Etot = E + N;
    const int NB = (N + CH - 1) / CH;     // scan chunks
    const size_t NP = (size_t)NB * CH;    // padded node count

    const size_t common =
        ((size_t)N * H1 * 4 + 255 & ~(size_t)255) * 2 +   // asrc1, adst1
        (((size_t)N * 4 + 255) & ~(size_t)255) * 2 +       // asrc2, adst2
        512 +                                              // wsrc, wdst
        (((size_t)NP * 4 + 255) & ~(size_t)255) * 2 +      // deg, cursor
        (((size_t)(NP + 1) * 4 + 255) & ~(size_t)255) +    // ptr
        (((size_t)NB * 4 + 255) & ~(size_t)255) * 2 +      // chunkSum, chunkOff
        (((size_t)Etot * 4 + 255) & ~(size_t)255) +        // edge_src
        (64 * XPAD * 2 + 256) +                            // Wb (bf16 W1)
        4096;                                              // slack
    const bool f32path = ws_size >= common + 2 * ((size_t)N * C1 * 4 + 256);

    char* ws = (char*)d_ws;
    size_t off = 0;
    auto alloc = [&](size_t bytes) -> void* {
        void* p = ws + off;
        off = (off + bytes + 255) & ~(size_t)255;
        return p;
    };
    const size_t es = f32path ? 4 : 2;
    void*  h1v    = alloc((size_t)N * C1 * es);   // aliased: binned CSR records, later aggv
    void*  hmidv  = alloc((size_t)N * C1 * es);   // aliased: bin control arrays during CSR
    float* asrc1  = (float*)alloc((size_t)N * H1 * 4);
    float* adst1  = (float*)alloc((size_t)N * H1 * 4);
    float* asrc2  = (float*)alloc((size_t)N * 4);
    float* adst2  = (float*)alloc((size_t)N * 4);
    float* wsrc   = (float*)alloc(64 * 4);
    float* wdst   = (float*)alloc(64 * 4);
    int*   deg    = (int*)alloc(NP * 4);
    int*   ptr    = (int*)alloc((NP + 1) * 4);
    int*   cursor = (int*)alloc(NP * 4);
    int*   chunkSum = (int*)alloc((size_t)NB * 4);
    int*   chunkOff = (int*)alloc((size_t)NB * 4);
    int*   edge_src = (int*)alloc((size_t)Etot * 4);
    unsigned short* Wb = (unsigned short*)alloc(64 * XPAD * 2);

    const int nodeBlocks = (N + 3) / 4;
    const int g1Blocks = (N + 63) / 64;
    const int g2Blocks = (N + NPB2 - 1) / NPB2;

    // ---- W1 -> bf16 padded (independent; do first) ----
    k_wcvt<<<32, 256, 0, stream>>>(W1, Wb);

    // ---- CSR build (dst-indexed) ----
    const int nbins = (N + NPBIN - 1) / NPBIN;
    const bool binpath = (N <= (1 << 17)) &&
                         ((size_t)Etot * 4 <= (size_t)N * C1 * es);
    if (binpath) {
        int* binned = (int*)h1v;                   // Etot ints
        int* binCnt = (int*)hmidv;                 // nbins
        int* binOff = binCnt + 1056;               // nbins+1
        int* binCur = binOff + 1056;               // nbins
        const int binBlocks = (Etot + TILEB - 1) / TILEB;
        hipMemsetAsync(binCnt, 0, (size_t)nbins * 4, stream);
        k_binhist<<<binBlocks, 256, 0, stream>>>(ei, E, N, nbins, binCnt);
        k_binscan<<<1, 256, 0, stream>>>(binCnt, binOff, binCur, nbins);
        k_bin<<<binBlocks, 256, 0, stream>>>(ei, E, N, nbins, binCur, binned);
        k_binptr<<<nbins, 256, 0, stream>>>(binOff, binned, ptr, edge_src, N, nbins);
    } else {
        hipMemsetAsync(deg, 0, NP * 4, stream);
        k_count<<<2048, 256, 0, stream>>>(ei, E, N, deg);
        k_scanA<<<NB, 256, 0, stream>>>(deg, ptr, chunkSum);
        k_scanB<<<1, 64, 0, stream>>>(chunkSum, chunkOff, NB, ptr + N);
        k_scanC<<<NB, 256, 0, stream>>>(ptr, cursor, chunkOff, N);
        k_scatter<<<2048, 256, 0, stream>>>(ei, E, N, cursor, edge_src);
    }

    k_wvec<<<1, 128, 0, stream>>>(W2, a_src2, a_dst2, wsrc, wdst);

    if (f32path) {
        float* h1 = (float*)h1v; float* hmid = (float*)hmidv;
        k_gemm1<float><<<g1Blocks, 256, 0, stream>>>(x, Wb, a_src1, a_dst1, h1, asrc1, adst1, N);
        k_agg1<float><<<nodeBlocks, 256, 0, stream>>>(ptr, edge_src, h1, asrc1, adst1, b1,
                                                      wsrc, wdst, hmid, asrc2, adst2, N);
        float* aggv = (float*)h1v;   // h1 dead after agg1
        k_agg2<float><<<nodeBlocks, 256, 0, stream>>>(ptr, edge_src, hmid, asrc2, adst2, aggv, N);
        k_gemm2<float><<<g2Blocks, 256, 0, stream>>>(aggv, W2, b2, out, N);
    } else {
        __hip_bfloat16* h1 = (__hip_bfloat16*)h1v; __hip_bfloat16* hmid = (__hip_bfloat16*)hmidv;
        k_gemm1<__hip_bfloat16><<<g1Blocks, 256, 0, stream>>>(x, Wb, a_src1, a_dst1, h1, asrc1, adst1, N);
        k_agg1<__hip_bfloat16><<<nodeBlocks, 256, 0, stream>>>(ptr, edge_src, h1, asrc1, adst1, b1,
                                                               wsrc, wdst, hmid, asrc2, adst2, N);
        __hip_bfloat16* aggv = (__hip_bfloat16*)h1v;   // h1 dead after agg1
        k_agg2<__hip_bfloat16><<<nodeBlocks, 256, 0, stream>>>(ptr, edge_src, hmid, asrc2, adst2, aggv, N);
        k_gemm2<__hip_bfloat16><<<g2Blocks, 256, 0, stream>>>(aggv, W2, b2, out, N);
    }
}

// Round 10
// 335.611 us; speedup vs baseline: 1.1061x; 1.0266x over previous
//
#include <hip/hip_runtime.h>
#include <hip/hip_bf16.h>
#include <cstdint>

#define H1 8
#define C1 64      // H1*D1
#define D2 128
#define FIN 256
#define NEG 0.2f
#define EPSS 1e-16f
#define CH 1024    // nodes per scan chunk
#define XPAD 264   // Wb global row stride in bf16 (c-major)
#define XQ 72      // gemm1 LDS quarter-K row stride in ushort (144 B)
#define HP 68      // gemm1 epilogue f32 row stride
#define NPBIN 128  // nodes per bin (CSR binning)
#define TILEB 4096 // edges per k_bin block
#define MAXD1 128  // agg1 fast-path degree cap
#define MAXD2 256  // agg2 fast-path degree cap

template<typename T> __device__ __forceinline__ float toF(T v);
template<> __device__ __forceinline__ float toF<float>(float v) { return v; }
template<> __device__ __forceinline__ float toF<__hip_bfloat16>(__hip_bfloat16 v) { return __bfloat162float(v); }
template<typename T> __device__ __forceinline__ T fromF(float v);
template<> __device__ __forceinline__ float fromF<float>(float v) { return v; }
template<> __device__ __forceinline__ __hip_bfloat16 fromF<__hip_bfloat16>(float v) { return __float2bfloat16(v); }

__device__ __forceinline__ float bcast_lane(float v, int lane) {
    return __int_as_float(__builtin_amdgcn_readlane(__float_as_int(v), lane));
}

__device__ __forceinline__ unsigned pk_bf16(float lo, float hi) {
    unsigned a = (unsigned)__bfloat16_as_ushort(__float2bfloat16(lo));
    unsigned b = (unsigned)__bfloat16_as_ushort(__float2bfloat16(hi));
    return a | (b << 16);
}

__device__ __forceinline__ float bf16u_toF(unsigned short u) {
    unsigned v = ((unsigned)u) << 16;
    return __uint_as_float(v);
}

typedef __attribute__((ext_vector_type(8))) short bf16x8;
typedef __attribute__((ext_vector_type(4))) float f32x4;

// online-softmax chain update (fallback path)
__device__ __forceinline__ void chain_upd(float ev, float hv,
                                          float& m, float& s, float& a)
{
    float mn = fmaxf(m, ev);
    float sc = __expf(m - mn);
    float p  = __expf(ev - mn);
    s = fmaf(s, sc, p);
    a = fmaf(a, sc, p * hv);
    m = mn;
}

// ---------------- W1 -> bf16 padded [c][k] layout (once) ----------------
__global__ __launch_bounds__(256) void k_wcvt(const float* __restrict__ W1,
    unsigned short* __restrict__ Wb)
{
    int t = blockIdx.x * 256 + threadIdx.x;       // 8192 threads: c=t>>7, kp=t&127
    int c = t >> 7, kp = t & 127;
    if (c < C1) {
        float f0 = W1[(2 * kp) * C1 + c];
        float f1 = W1[(2 * kp + 1) * C1 + c];
        *reinterpret_cast<unsigned*>(&Wb[c * XPAD + 2 * kp]) = pk_bf16(f0, f1);
    }
}

// ---------------- W2 -> bf16 [k][j] (once) ----------------
__global__ __launch_bounds__(256) void k_w2cvt(const float* __restrict__ W2,
    unsigned short* __restrict__ W2b)
{
    int t = blockIdx.x * 256 + threadIdx.x;       // 4096 threads
    if (t < C1 * D2 / 2) {
        float f0 = W2[2 * t], f1 = W2[2 * t + 1];
        *reinterpret_cast<unsigned*>(&W2b[2 * t]) = pk_bf16(f0, f1);
    }
}

// ---------------- GEMM1 v4 (MFMA, K-quarter split, 18.4 KB LDS) ----------------
template<typename T>
__global__ __launch_bounds__(256) void k_gemm1(const float* __restrict__ x,
    const unsigned short* __restrict__ Wb, const float* __restrict__ a_src1,
    const float* __restrict__ a_dst1, T* __restrict__ h1,
    float* __restrict__ asrc1, float* __restrict__ adst1, int N)
{
    __shared__ alignas(16) char smem[2 * 64 * XQ * 2];   // 18432 B
    unsigned short* Xs = (unsigned short*)smem;
    unsigned short* Wt = (unsigned short*)(smem + 64 * XQ * 2);
    int tid = threadIdx.x;
    int wave = tid >> 6, lane = tid & 63;
    int nodeBase = blockIdx.x * 64;
    int m = lane & 15, kg = lane >> 4;
    int arow = wave * 16 + m;

    f32x4 acc[4];
    #pragma unroll
    for (int t = 0; t < 4; ++t) acc[t] = (f32x4){0.f, 0.f, 0.f, 0.f};

    #pragma unroll
    for (int kh = 0; kh < 4; ++kh) {
        // stage W quarter (8 KB bf16 copy from L2): 512 x 16B
        for (int i = tid; i < 512; i += 256) {
            int c = i >> 3, ch = i & 7;
            *reinterpret_cast<uint4*>(&Wt[c * XQ + ch * 8]) =
                *reinterpret_cast<const uint4*>(&Wb[c * XPAD + kh * 64 + ch * 8]);
        }
        // stage x quarter: 64 rows x 16 float4
        for (int i = tid; i < 1024; i += 256) {
            int r = i >> 4, q = i & 15;
            int n = nodeBase + r;
            float4 v = (n < N) ? reinterpret_cast<const float4*>(x)[(size_t)n * 64 + kh * 16 + q]
                               : make_float4(0.f, 0.f, 0.f, 0.f);
            *reinterpret_cast<uint2*>(&Xs[r * XQ + q * 4]) =
                make_uint2(pk_bf16(v.x, v.y), pk_bf16(v.z, v.w));
        }
        __syncthreads();
        #pragma unroll
        for (int ks = 0; ks < 2; ++ks) {
            int k0 = ks * 32 + kg * 8;
            bf16x8 a = *reinterpret_cast<const bf16x8*>(&Xs[arow * XQ + k0]);
            #pragma unroll
            for (int t = 0; t < 4; ++t) {
                bf16x8 b = *reinterpret_cast<const bf16x8*>(&Wt[(t * 16 + m) * XQ + k0]);
                acc[t] = __builtin_amdgcn_mfma_f32_16x16x32_bf16(a, b, acc[t], 0, 0, 0);
            }
        }
        __syncthreads();
    }

    // epilogue: spill acc to LDS (Hs aliases smem: 64*68*4 = 17408 <= 18432)
    float* Hs = reinterpret_cast<float*>(smem);
    int crow = (lane >> 4) * 4;
    #pragma unroll
    for (int t = 0; t < 4; ++t)
        #pragma unroll
        for (int r = 0; r < 4; ++r)
            Hs[(wave * 16 + crow + r) * HP + t * 16 + m] = acc[t][r];
    __syncthreads();

    float as_l = a_src1[lane], ad_l = a_dst1[lane];
    int n0 = nodeBase + wave * 16;
    #pragma unroll
    for (int i = 0; i < 16; ++i) {
        int n = n0 + i;
        if (n >= N) break;
        float hv = Hs[(wave * 16 + i) * HP + lane];
        h1[(size_t)n * C1 + lane] = fromF<T>(hv);
        float vs = hv * as_l, vd = hv * ad_l;
        #pragma unroll
        for (int off = 1; off < 8; off <<= 1) {
            vs += __shfl_xor(vs, off);
            vd += __shfl_xor(vd, off);
        }
        if ((lane & 7) == 0) {
            asrc1[n * H1 + (lane >> 3)] = vs;
            adst1[n * H1 + (lane >> 3)] = vd;
        }
    }
}

// ---------------- wsrc/wdst = W2 @ a_src2 / W2 @ a_dst2  (64 each) ----------------
__global__ __launch_bounds__(128) void k_wvec(const float* __restrict__ W2,
    const float* __restrict__ a_src2, const float* __restrict__ a_dst2,
    float* __restrict__ wsrc, float* __restrict__ wdst)
{
    int t = threadIdx.x;
    int k = t & 63;
    const float* a = (t < 64) ? a_src2 : a_dst2;
    float s = 0.f;
    for (int c = 0; c < D2; ++c) s = fmaf(W2[k * D2 + c], a[c], s);
    if (t < 64) wsrc[k] = s; else wdst[k] = s;
}

// ---------------- CSR build: binned path (N <= 2^17) ----------------
__global__ __launch_bounds__(256) void k_binhist(const int* __restrict__ ei, int E, int N,
    int nbins, int* __restrict__ binCnt)
{
    __shared__ int lcnt[1024];
    int tot = E + N;
    int t0 = blockIdx.x * TILEB;
    int cnt = min(TILEB, tot - t0);
    for (int i = threadIdx.x; i < nbins; i += 256) lcnt[i] = 0;
    __syncthreads();
    for (int i = threadIdx.x; i < cnt; i += 256) {
        int e = t0 + i;
        int dst = (e < E) ? ei[(size_t)E + e] : (e - E);
        atomicAdd(&lcnt[dst >> 7], 1);
    }
    __syncthreads();
    for (int i = threadIdx.x; i < nbins; i += 256)
        if (lcnt[i]) atomicAdd(&binCnt[i], lcnt[i]);
}

__global__ __launch_bounds__(256) void k_binscan(const int* __restrict__ binCnt,
    int* __restrict__ binOff, int* __restrict__ binCur, int nbins)
{
    __shared__ int wtot[4];
    int t = threadIdx.x, lane = t & 63, wave = t >> 6;
    int v[4];
    #pragma unroll
    for (int j = 0; j < 4; ++j) {
        int idx = t * 4 + j;
        v[j] = (idx < nbins) ? binCnt[idx] : 0;
    }
    int s = v[0] + v[1] + v[2] + v[3];
    int incl = s;
    #pragma unroll
    for (int off = 1; off < 64; off <<= 1) {
        int tt = __shfl_up(incl, off);
        if (lane >= off) incl += tt;
    }
    if (lane == 63) wtot[wave] = incl;
    __syncthreads();
    int woff = 0;
    #pragma unroll
    for (int w = 0; w < 4; ++w) if (w < wave) woff += wtot[w];
    int run = woff + incl - s;
    #pragma unroll
    for (int j = 0; j < 4; ++j) {
        int idx = t * 4 + j;
        if (idx < nbins) { binOff[idx] = run; binCur[idx] = run; }
        run += v[j];
    }
    if (t == 255) binOff[nbins] = woff + incl;
}

__global__ __launch_bounds__(256) void k_bin(const int* __restrict__ ei, int E, int N,
    int nbins, int* __restrict__ binCur, int* __restrict__ binned)
{
    __shared__ int recs[TILEB];
    __shared__ unsigned short bns[TILEB];
    __shared__ int lcnt[1024];
    __shared__ int lbase[1024];
    int tot = E + N;
    int t0 = blockIdx.x * TILEB;
    int cnt = min(TILEB, tot - t0);
    for (int i = threadIdx.x; i < nbins; i += 256) lcnt[i] = 0;
    __syncthreads();
    for (int i = threadIdx.x; i < cnt; i += 256) {
        int e = t0 + i;
        int src, dst;
        if (e < E) { src = ei[e]; dst = ei[(size_t)E + e]; }
        else       { src = e - E; dst = src; }
        int b = dst >> 7;
        recs[i] = src | ((dst & 127) << 17);
        bns[i] = (unsigned short)b;
        atomicAdd(&lcnt[b], 1);
    }
    __syncthreads();
    for (int i = threadIdx.x; i < nbins; i += 256) {
        int c = lcnt[i];
        if (c) lbase[i] = atomicAdd(&binCur[i], c);
        lcnt[i] = 0;
    }
    __syncthreads();
    for (int i = threadIdx.x; i < cnt; i += 256) {
        int b = bns[i];
        int lp = atomicAdd(&lcnt[b], 1);
        binned[lbase[b] + lp] = recs[i];
    }
}

// fused: per-bin degree count -> in-bin prefix scan -> ptr write -> scatter
__global__ __launch_bounds__(256) void k_binptr(const int* __restrict__ binOff,
    const int* __restrict__ binned, int* __restrict__ ptr,
    int* __restrict__ edge_src, int N, int nbins)
{
    __shared__ int cnt[NPBIN];
    __shared__ int cur[NPBIN];
    __shared__ int w0tot;
    int b = blockIdx.x, t = threadIdx.x;
    int s0 = binOff[b], s1 = binOff[b + 1];
    if (t < NPBIN) cnt[t] = 0;
    __syncthreads();
    for (int i = s0 + t; i < s1; i += 256)
        atomicAdd(&cnt[binned[i] >> 17], 1);
    __syncthreads();
    int v = 0, incl = 0;
    if (t < NPBIN) {
        int lane = t & 63;
        v = cnt[t];
        incl = v;
        #pragma unroll
        for (int off = 1; off < 64; off <<= 1) {
            int tt = __shfl_up(incl, off);
            if (lane >= off) incl += tt;
        }
        if (t == 63) w0tot = incl;
    }
    __syncthreads();
    if (t < NPBIN) {
        int base = s0 + ((t >= 64) ? w0tot : 0);
        int excl = base + incl - v;
        int node = b * NPBIN + t;
        if (node < N) ptr[node] = excl;
        cur[t] = excl;
    }
    if (b == nbins - 1 && t == 0) ptr[N] = s1;
    __syncthreads();
    for (int i = s0 + t; i < s1; i += 256) {
        int rec = binned[i];
        int p = atomicAdd(&cur[rec >> 17], 1);
        edge_src[p] = rec & 0x1FFFF;
    }
}

// ---------------- CSR build: fallback path ----------------
__global__ void k_count(const int* __restrict__ ei, int E, int N,
                        int* __restrict__ deg)
{
    int tot = E + N;
    for (int e = blockIdx.x * blockDim.x + threadIdx.x; e < tot;
         e += gridDim.x * blockDim.x) {
        int dst = (e < E) ? ei[(size_t)E + e] : (e - E);
        atomicAdd(&deg[dst], 1);
    }
}

__global__ void k_scatter(const int* __restrict__ ei, int E, int N,
                          int* __restrict__ cursor, int* __restrict__ edge_src)
{
    int tot = E + N;
    for (int e = blockIdx.x * blockDim.x + threadIdx.x; e < tot;
         e += gridDim.x * blockDim.x) {
        int src, dst;
        if (e < E) { src = ei[e]; dst = ei[(size_t)E + e]; }
        else       { src = e - E; dst = e - E; }
        int pos = atomicAdd(&cursor[dst], 1);
        edge_src[pos] = src;
    }
}

__global__ __launch_bounds__(256) void k_scanA(const int* __restrict__ deg,
    int* __restrict__ ptr, int* __restrict__ chunkSum)
{
    __shared__ int wtot[4];
    int b = blockIdx.x, t = threadIdx.x;
    int lane = t & 63, wave = t >> 6;
    int4 v = reinterpret_cast<const int4*>(deg + (size_t)b * CH)[t];
    int s = v.x + v.y + v.z + v.w;
    int incl = s;
    #pragma unroll
    for (int off = 1; off < 64; off <<= 1) {
        int tt = __shfl_up(incl, off);
        if (lane >= off) incl += tt;
    }
    if (lane == 63) wtot[wave] = incl;
    __syncthreads();
    int woff = 0;
    #pragma unroll
    for (int w = 0; w < 4; ++w) if (w < wave) woff += wtot[w];
    int excl = woff + incl - s;
    int i0 = b * CH + t * 4;
    ptr[i0 + 0] = excl;
    ptr[i0 + 1] = excl + v.x;
    ptr[i0 + 2] = excl + v.x + v.y;
    ptr[i0 + 3] = excl + v.x + v.y + v.z;
    if (t == 255) chunkSum[b] = woff + incl;
}

__global__ void k_scanB(const int* __restrict__ chunkSum, int* __restrict__ chunkOff,
                        int NB, int* __restrict__ ptrN)
{
    if (threadIdx.x == 0) {
        int c = 0;
        for (int b = 0; b < NB; ++b) { chunkOff[b] = c; c += chunkSum[b]; }
        *ptrN = c;
    }
}

__global__ __launch_bounds__(256) void k_scanC(int* __restrict__ ptr,
    int* __restrict__ cursor, const int* __restrict__ chunkOff, int N)
{
    int b = blockIdx.x;
    int off = chunkOff[b];
    int i0 = b * CH + threadIdx.x * 4;
    #pragma unroll
    for (int k = 0; k < 4; ++k) {
        int i = i0 + k;
        if (i < N) { int v = ptr[i] + off; ptr[i] = v; cursor[i] = v; }
    }
}

// -------- Layer-1 aggregation: two-phase softmax, 8-deep gather MLP --------
template<typename T>
__global__ __launch_bounds__(256) void k_agg1(const int* __restrict__ ptr,
    const int* __restrict__ edge_src, const T* __restrict__ h1,
    const float* __restrict__ asrc1, const float* __restrict__ adst1,
    const float* __restrict__ b1, const float* __restrict__ wsrc,
    const float* __restrict__ wdst, T* __restrict__ hmid,
    float* __restrict__ asrc2, float* __restrict__ adst2, int N)
{
    __shared__ float S1[4 * MAXD1 * H1];           // 16 KB per-wave stash
    int wave = threadIdx.x >> 6, lane = threadIdx.x & 63;
    float* st = S1 + wave * (MAXD1 * H1);
    int n = blockIdx.x * 4 + wave;
    if (n >= N) return;
    int start = ptr[n], end = ptr[n + 1];
    int deg = end - start;
    int h = lane >> 3;
    float o;

    if (deg <= MAXD1) {
        // ---- phase 1 ----
        int e_loc = lane >> 3, hh = lane & 7;
        float adsth = adst1[n * H1 + hh];
        float mloc = -1e30f;
        for (int eb = start, base = 0; eb < end; eb += 8, base += 64) {
            int e = eb + e_loc;
            float ev = -1e30f;
            if (e < end) {
                int s = edge_src[e];
                ev = asrc1[s * H1 + hh] + adsth;
                ev = ev > 0.f ? ev : NEG * ev;
                st[base + lane] = ev;
            }
            mloc = fmaxf(mloc, ev);
        }
        mloc = fmaxf(mloc, __shfl_xor(mloc, 8));
        mloc = fmaxf(mloc, __shfl_xor(mloc, 16));
        mloc = fmaxf(mloc, __shfl_xor(mloc, 32));
        __builtin_amdgcn_wave_barrier();
        float sloc = 0.f;
        for (int eb = start, base = 0; eb < end; eb += 8, base += 64) {
            if (eb + e_loc < end) {
                float p = __expf(st[base + lane] - mloc);
                st[base + lane] = p;
                sloc += p;
            }
        }
        sloc += __shfl_xor(sloc, 8);
        sloc += __shfl_xor(sloc, 16);
        sloc += __shfl_xor(sloc, 32);
        float inv = 1.f / (sloc + EPSS);
        __builtin_amdgcn_wave_barrier();
        float inv_c = __shfl(inv, h);               // head-layout -> channel-layout

        // ---- phase 2: 8-deep independent gathers ----
        float a0 = 0.f, a1 = 0.f, a2 = 0.f, a3 = 0.f;
        float a4 = 0.f, a5 = 0.f, a6 = 0.f, a7 = 0.f;
        int e = start;
        for (; e + 8 <= end; e += 8) {
            int r = e - start;
            int i0 = edge_src[e + 0]; int i1 = edge_src[e + 1];
            int i2 = edge_src[e + 2]; int i3 = edge_src[e + 3];
            int i4 = edge_src[e + 4]; int i5 = edge_src[e + 5];
            int i6 = edge_src[e + 6]; int i7 = edge_src[e + 7];
            float w0 = st[(r + 0) * H1 + h]; float w1 = st[(r + 1) * H1 + h];
            float w2 = st[(r + 2) * H1 + h]; float w3 = st[(r + 3) * H1 + h];
            float w4 = st[(r + 4) * H1 + h]; float w5 = st[(r + 5) * H1 + h];
            float w6 = st[(r + 6) * H1 + h]; float w7 = st[(r + 7) * H1 + h];
            a0 = fmaf(w0, toF(h1[((size_t)(unsigned)i0 << 6) + lane]), a0);
            a1 = fmaf(w1, toF(h1[((size_t)(unsigned)i1 << 6) + lane]), a1);
            a2 = fmaf(w2, toF(h1[((size_t)(unsigned)i2 << 6) + lane]), a2);
            a3 = fmaf(w3, toF(h1[((size_t)(unsigned)i3 << 6) + lane]), a3);
            a4 = fmaf(w4, toF(h1[((size_t)(unsigned)i4 << 6) + lane]), a4);
            a5 = fmaf(w5, toF(h1[((size_t)(unsigned)i5 << 6) + lane]), a5);
            a6 = fmaf(w6, toF(h1[((size_t)(unsigned)i6 << 6) + lane]), a6);
            a7 = fmaf(w7, toF(h1[((size_t)(unsigned)i7 << 6) + lane]), a7);
        }
        for (; e < end; ++e) {
            int s = edge_src[e];
            a0 = fmaf(st[(e - start) * H1 + h],
                      toF(h1[((size_t)(unsigned)s << 6) + lane]), a0);
        }
        float acc = ((a0 + a1) + (a2 + a3)) + ((a4 + a5) + (a6 + a7));
        o = acc * inv_c;
    } else {
        // ---- fallback: 8-chain online softmax ----
        float adst = adst1[n * H1 + h];
        float m[8], ss[8], aa[8];
        #pragma unroll
        for (int j = 0; j < 8; ++j) { m[j] = -1e30f; ss[j] = 0.f; aa[j] = 0.f; }
        int e = start;
        for (; e + 8 <= end; e += 8) {
            int idx[8];
            #pragma unroll
            for (int j = 0; j < 8; ++j) idx[j] = edge_src[e + j];
            #pragma unroll
            for (int j = 0; j < 8; ++j) {
                float t = asrc1[idx[j] * H1 + h] + adst;
                t = t > 0.f ? t : NEG * t;
                chain_upd(t, toF(h1[((size_t)(unsigned)idx[j] << 6) + lane]),
                          m[j], ss[j], aa[j]);
            }
        }
        for (; e < end; ++e) {
            int s = edge_src[e];
            float t = asrc1[s * H1 + h] + adst;
            t = t > 0.f ? t : NEG * t;
            chain_upd(t, toF(h1[((size_t)(unsigned)s << 6) + lane]), m[0], ss[0], aa[0]);
        }
        float M = fmaxf(fmaxf(fmaxf(m[0], m[1]), fmaxf(m[2], m[3])),
                        fmaxf(fmaxf(m[4], m[5]), fmaxf(m[6], m[7])));
        float sum = 0.f, acc = 0.f;
        #pragma unroll
        for (int j = 0; j < 8; ++j) {
            float sc = __expf(m[j] - M);
            sum = fmaf(ss[j], sc, sum);
            acc = fmaf(aa[j], sc, acc);
        }
        o = acc / (sum + EPSS);
    }

    o = o + b1[lane];
    o = o > 0.f ? o : (expf(o) - 1.f);   // ELU
    hmid[(size_t)n * C1 + lane] = fromF<T>(o);
    float vs = o * wsrc[lane];
    float vd = o * wdst[lane];
    #pragma unroll
    for (int off = 1; off < 64; off <<= 1) {
        vs += __shfl_xor(vs, off);
        vd += __shfl_xor(vd, off);
    }
    if (lane == 0) { asrc2[n] = vs; adst2[n] = vd; }
}

// ---- Layer-2 fused: two-phase softmax aggregation + W2 GEMM + bias ----
// LDS = 16 KB (W2 bf16) + 4 KB stash = 20 KB -> 8 blocks/CU (wave cap, no loss).
template<typename T>
__global__ __launch_bounds__(256) void k_agg2out(const int* __restrict__ ptr,
    const int* __restrict__ edge_src, const T* __restrict__ hmid,
    const float* __restrict__ asrc2, const float* __restrict__ adst2,
    const unsigned short* __restrict__ W2b, const float* __restrict__ b2,
    float* __restrict__ out, int N)
{
    __shared__ unsigned short Ws[C1 * D2];         // 16 KB bf16
    __shared__ float S2[4 * MAXD2];                // 4 KB per-wave stash
    for (int i = threadIdx.x; i < C1 * D2 / 8; i += 256)
        reinterpret_cast<uint4*>(Ws)[i] = reinterpret_cast<const uint4*>(W2b)[i];
    __syncthreads();

    int wave = threadIdx.x >> 6, lane = threadIdx.x & 63;
    float* st = S2 + wave * MAXD2;
    int n = blockIdx.x * 4 + wave;
    if (n >= N) return;
    int start = ptr[n], end = ptr[n + 1];
    int deg = end - start;
    float adst = adst2[n];
    float aggv;

    if (deg <= MAXD2) {
        // ---- phase 1: lanes over edges ----
        float mloc = -1e30f;
        for (int e = start + lane; e < end; e += 64) {
            int s = edge_src[e];
            float ev = asrc2[s] + adst;
            ev = ev > 0.f ? ev : NEG * ev;
            st[e - start] = ev;
            mloc = fmaxf(mloc, ev);
        }
        #pragma unroll
        for (int off = 1; off < 64; off <<= 1)
            mloc = fmaxf(mloc, __shfl_xor(mloc, off));
        __builtin_amdgcn_wave_barrier();
        float sloc = 0.f;
        for (int e = start + lane; e < end; e += 64) {
            float p = __expf(st[e - start] - mloc);
            st[e - start] = p;
            sloc += p;
        }
        #pragma unroll
        for (int off = 1; off < 64; off <<= 1)
            sloc += __shfl_xor(sloc, off);
        float inv = 1.f / (sloc + EPSS);
        __builtin_amdgcn_wave_barrier();

        // ---- phase 2: 8-deep independent gathers ----
        float a0 = 0.f, a1 = 0.f, a2 = 0.f, a3 = 0.f;
        float a4 = 0.f, a5 = 0.f, a6 = 0.f, a7 = 0.f;
        int e = start;
        for (; e + 8 <= end; e += 8) {
            int r = e - start;
            int i0 = edge_src[e + 0]; int i1 = edge_src[e + 1];
            int i2 = edge_src[e + 2]; int i3 = edge_src[e + 3];
            int i4 = edge_src[e + 4]; int i5 = edge_src[e + 5];
            int i6 = edge_src[e + 6]; int i7 = edge_src[e + 7];
            a0 = fmaf(st[r + 0], toF(hmid[((size_t)(unsigned)i0 << 6) + lane]), a0);
            a1 = fmaf(st[r + 1], toF(hmid[((size_t)(unsigned)i1 << 6) + lane]), a1);
            a2 = fmaf(st[r + 2], toF(hmid[((size_t)(unsigned)i2 << 6) + lane]), a2);
            a3 = fmaf(st[r + 3], toF(hmid[((size_t)(unsigned)i3 << 6) + lane]), a3);
            a4 = fmaf(st[r + 4], toF(hmid[((size_t)(unsigned)i4 << 6) + lane]), a4);
            a5 = fmaf(st[r + 5], toF(hmid[((size_t)(unsigned)i5 << 6) + lane]), a5);
            a6 = fmaf(st[r + 6], toF(hmid[((size_t)(unsigned)i6 << 6) + lane]), a6);
            a7 = fmaf(st[r + 7], toF(hmid[((size_t)(unsigned)i7 << 6) + lane]), a7);
        }
        for (; e < end; ++e) {
            int s = edge_src[e];
            a0 = fmaf(st[e - start], toF(hmid[((size_t)(unsigned)s << 6) + lane]), a0);
        }
        float acc = ((a0 + a1) + (a2 + a3)) + ((a4 + a5) + (a6 + a7));
        aggv = acc * inv;
    } else {
        // ---- fallback: 8-chain online softmax ----
        float m[8], ss[8], aa[8];
        #pragma unroll
        for (int j = 0; j < 8; ++j) { m[j] = -1e30f; ss[j] = 0.f; aa[j] = 0.f; }
        int e = start;
        for (; e + 8 <= end; e += 8) {
            int idx[8];
            #pragma unroll
            for (int j = 0; j < 8; ++j) idx[j] = edge_src[e + j];
            #pragma unroll
            for (int j = 0; j < 8; ++j) {
                float t = asrc2[idx[j]] + adst;
                t = t > 0.f ? t : NEG * t;
                chain_upd(t, toF(hmid[((size_t)(unsigned)idx[j] << 6) + lane]),
                          m[j], ss[j], aa[j]);
            }
        }
        for (; e < end; ++e) {
            int s = edge_src[e];
            float t = asrc2[s] + adst;
            t = t > 0.f ? t : NEG * t;
            chain_upd(t, toF(hmid[((size_t)(unsigned)s << 6) + lane]), m[0], ss[0], aa[0]);
        }
        float M = fmaxf(fmaxf(fmaxf(m[0], m[1]), fmaxf(m[2], m[3])),
                        fmaxf(fmaxf(m[4], m[5]), fmaxf(m[6], m[7])));
        float sum = 0.f, acc = 0.f;
        #pragma unroll
        for (int j = 0; j < 8; ++j) {
            float sc = __expf(m[j] - M);
            sum = fmaf(ss[j], sc, sum);
            acc = fmaf(aa[j], sc, acc);
        }
        aggv = acc / (sum + EPSS);
    }

    // ---- fused W2 GEMM epilogue (bf16 W2 from LDS; lane-contiguous = conflict-free) ----
    float acc0 = 0.f, acc1 = 0.f;
    #pragma unroll
    for (int k = 0; k < 64; ++k) {
        float xk = bcast_lane(aggv, k);
        float w0 = bf16u_toF(Ws[k * D2 + lane]);
        float w1 = bf16u_toF(Ws[k * D2 + 64 + lane]);
        acc0 = fmaf(xk, w0, acc0);
        acc1 = fmaf(xk, w1, acc1);
    }
    out[(size_t)n * D2 + lane]      = acc0 + b2[lane];
    out[(size_t)n * D2 + 64 + lane] = acc1 + b2[64 + lane];
}

extern "C" void kernel_launch(void* const* d_in, const int* in_sizes, int n_in,
                              void* d_out, int out_size, void* d_ws, size_t ws_size,
                              hipStream_t stream)
{
    const float* x      = (const float*)d_in[0];
    const int*   ei     = (const int*)d_in[1];
    const float* W1     = (const float*)d_in[2];
    const float* a_src1 = (const float*)d_in[3];
    const float* a_dst1 = (const float*)d_in[4];
    const float* b1     = (const float*)d_in[5];
    const float* W2     = (const float*)d_in[6];
    const float* a_src2 = (const float*)d_in[7];
    const float* a_dst2 = (const float*)d_in[8];
    const float* b2     = (const float*)d_in[9];
    float* out = (float*)d_out;

    const int N = in_sizes[0] / FIN;
    const int E = in_sizes[1] / 2;
    const int Etot = E + N;
    const int NB = (N + CH - 1) / CH;     // scan chunks
    const size_t NP = (size_t)NB * CH;    // padded node count

    const size_t common =
        ((size_t)N * H1 * 4 + 255 & ~(size_t)255) * 2 +   // asrc1, adst1
        (((size_t)N * 4 + 255) & ~(size_t)255) * 2 +       // asrc2, adst2
        512 +                                              // wsrc, wdst
        (((size_t)NP * 4 + 255) & ~(size_t)255) * 2 +      // deg, cursor
        (((size_t)(NP + 1) * 4 + 255) & ~(size_t)255) +    // ptr
        (((size_t)NB * 4 + 255) & ~(size_t)255) * 2 +      // chunkSum, chunkOff
        (((size_t)Etot * 4 + 255) & ~(size_t)255) +        // edge_src
        (64 * XPAD * 2 + 256) +                            // Wb (bf16 W1)
        (C1 * D2 * 2 + 256) +                              // W2b (bf16 W2)
        4096;                                              // slack
    const bool f32path = ws_size >= common + 2 * ((size_t)N * C1 * 4 + 256);

    char* ws = (char*)d_ws;
    size_t off = 0;
    auto alloc = [&](size_t bytes) -> void* {
        void* p = ws + off;
        off = (off + bytes + 255) & ~(size_t)255;
        return p;
    };
    const size_t es = f32path ? 4 : 2;
    void*  h1v    = alloc((size_t)N * C1 * es);   // aliased: binned CSR records
    void*  hmidv  = alloc((size_t)N * C1 * es);   // aliased: bin control arrays during CSR
    float* asrc1  = (float*)alloc((size_t)N * H1 * 4);
    float* adst1  = (float*)alloc((size_t)N * H1 * 4);
    float* asrc2  = (float*)alloc((size_t)N * 4);
    float* adst2  = (float*)alloc((size_t)N * 4);
    float* wsrc   = (float*)alloc(64 * 4);
    float* wdst   = (float*)alloc(64 * 4);
    int*   deg    = (int*)alloc(NP * 4);
    int*   ptr    = (int*)alloc((NP + 1) * 4);
    int*   cursor = (int*)alloc(NP * 4);
    int*   chunkSum = (int*)alloc((size_t)NB * 4);
    int*   chunkOff = (int*)alloc((size_t)NB * 4);
    int*   edge_src = (int*)alloc((size_t)Etot * 4);
    unsigned short* Wb  = (unsigned short*)alloc(64 * XPAD * 2);
    unsigned short* W2b = (unsigned short*)alloc(C1 * D2 * 2);

    const int nodeBlocks = (N + 3) / 4;
    const int g1Blocks = (N + 63) / 64;

    // ---- weight conversions (independent; do first) ----
    k_wcvt<<<32, 256, 0, stream>>>(W1, Wb);
    k_w2cvt<<<16, 256, 0, stream>>>(W2, W2b);

    // ---- CSR build (dst-indexed) ----
    const int nbins = (N + NPBIN - 1) / NPBIN;
    const bool binpath = (N <= (1 << 17)) &&
                         ((size_t)Etot * 4 <= (size_t)N * C1 * es);
    if (binpath) {
        int* binned = (int*)h1v;                   // Etot ints
        int* binCnt = (int*)hmidv;                 // nbins
        int* binOff = binCnt + 1056;               // nbins+1
        int* binCur = binOff + 1056;               // nbins
        const int binBlocks = (Etot + TILEB - 1) / TILEB;
        hipMemsetAsync(binCnt, 0, (size_t)nbins * 4, stream);
        k_binhist<<<binBlocks, 256, 0, stream>>>(ei, E, N, nbins, binCnt);
        k_binscan<<<1, 256, 0, stream>>>(binCnt, binOff, binCur, nbins);
        k_bin<<<binBlocks, 256, 0, stream>>>(ei, E, N, nbins, binCur, binned);
        k_binptr<<<nbins, 256, 0, stream>>>(binOff, binned, ptr, edge_src, N, nbins);
    } else {
        hipMemsetAsync(deg, 0, NP * 4, stream);
        k_count<<<2048, 256, 0, stream>>>(ei, E, N, deg);
        k_scanA<<<NB, 256, 0, stream>>>(deg, ptr, chunkSum);
        k_scanB<<<1, 64, 0, stream>>>(chunkSum, chunkOff, NB, ptr + N);
        k_scanC<<<NB, 256, 0, stream>>>(ptr, cursor, chunkOff, N);
        k_scatter<<<2048, 256, 0, stream>>>(ei, E, N, cursor, edge_src);
    }

    k_wvec<<<1, 128, 0, stream>>>(W2, a_src2, a_dst2, wsrc, wdst);

    if (f32path) {
        float* h1 = (float*)h1v; float* hmid = (float*)hmidv;
        k_gemm1<float><<<g1Blocks, 256, 0, stream>>>(x, Wb, a_src1, a_dst1, h1, asrc1, adst1, N);
        k_agg1<float><<<nodeBlocks, 256, 0, stream>>>(ptr, edge_src, h1, asrc1, adst1, b1,
                                                      wsrc, wdst, hmid, asrc2, adst2, N);
        k_agg2out<float><<<nodeBlocks, 256, 0, stream>>>(ptr, edge_src, hmid, asrc2, adst2,
                                                         W2b, b2, out, N);
    } else {
        __hip_bfloat16* h1 = (__hip_bfloat16*)h1v; __hip_bfloat16* hmid = (__hip_bfloat16*)hmidv;
        k_gemm1<__hip_bfloat16><<<g1Blocks, 256, 0, stream>>>(x, Wb, a_src1, a_dst1, h1, asrc1, adst1, N);
        k_agg1<__hip_bfloat16><<<nodeBlocks, 256, 0, stream>>>(ptr, edge_src, h1, asrc1, adst1, b1,
                                                               wsrc, wdst, hmid, asrc2, adst2, N);
        k_agg2out<__hip_bfloat16><<<nodeBlocks, 256, 0, stream>>>(ptr, edge_src, hmid, asrc2, adst2,
                                                                  W2b, b2, out, N);
    }
}